// Round 2
// baseline (5239.257 us; speedup 1.0000x reference)
//
#include <hip/hip_runtime.h>
#include <cstdint>

typedef __attribute__((ext_vector_type(8))) short short8;
typedef __attribute__((ext_vector_type(4))) float floatx4;

#define DEV __device__ __forceinline__

DEV short f2bf(float f) {
  unsigned u = __builtin_bit_cast(unsigned, f);
  u += 0x7fffu + ((u >> 16) & 1u);
  return (short)(u >> 16);
}
DEV float bf2f(short s) {
  unsigned u = ((unsigned)(unsigned short)s) << 16;
  return __builtin_bit_cast(float, u);
}
DEV float gelu_f(float x) {
  return 0.5f * x * (1.0f + erff(x * 0.70710678118654752f));
}
DEV void gload16(const void* g, void* l) {
  __builtin_amdgcn_global_load_lds((const __attribute__((address_space(1))) void*)g,
                                   (__attribute__((address_space(3))) void*)l,
                                   16, 0, 0);
}

// ---------------------------------------------------------------------------
// 128x128-tile bf16 MFMA GEMM.  C[M,N] = A[M,K] * Bw[N,K]^T + bias.
// Both A and Bw are K-contiguous bf16; K multiple of 32; M multiple of 128;
// Bw zero-padded to NT*128 rows.
// MODE 0: C = v + bias                  (bf16)
// MODE 1: C = gelu(v + bias)            (bf16)
// MODE 2: C = v + bias + pe[(row&127)*288 + col]  (bf16, input projection)
// ---------------------------------------------------------------------------
template<int MODE>
__global__ __launch_bounds__(256)
void gemm_kernel(const short* __restrict__ A, const short* __restrict__ Bw,
                 const float* __restrict__ bias, short* __restrict__ C,
                 const float* __restrict__ pe,
                 int K, int lda, int ldb, int ldc, int Nstore)
{
  __shared__ __align__(16) short As[128 * 32];
  __shared__ __align__(16) short Bs[128 * 32];
  const int tid  = threadIdx.x;
  const int wave = tid >> 6, lane = tid & 63;
  const int quad = lane >> 4, r16 = lane & 15;
  const int mt = blockIdx.x, nt = blockIdx.y;
  const int wm = (wave >> 1) * 64, wn = (wave & 1) * 64;

  const long Abase = (long)mt * 128 * lda;
  const long Bbase = (long)nt * 128 * ldb;

  // staging chunk c (16B) -> LDS offset c*16; round r: c = r*256 + tid
  const int row0 = tid >> 2,         cc0 = tid & 3;
  const int row1 = (256 + tid) >> 2, cc1 = tid & 3;

  floatx4 acc[4][4] = {};

  for (int k0 = 0; k0 < K; k0 += 32) {
    __syncthreads();
    gload16(A  + Abase + (long)row0 * lda + k0 + cc0 * 8, &As[(0 * 256 + wave * 64) * 8]);
    gload16(A  + Abase + (long)row1 * lda + k0 + cc1 * 8, &As[(1 * 256 + wave * 64) * 8]);
    gload16(Bw + Bbase + (long)row0 * ldb + k0 + cc0 * 8, &Bs[(0 * 256 + wave * 64) * 8]);
    gload16(Bw + Bbase + (long)row1 * ldb + k0 + cc1 * 8, &Bs[(1 * 256 + wave * 64) * 8]);
    __syncthreads();

    short8 af[4], bfr[4];
#pragma unroll
    for (int i = 0; i < 4; ++i)
      af[i] = *(const short8*)&As[(wm + i * 16 + r16) * 32 + quad * 8];
#pragma unroll
    for (int j = 0; j < 4; ++j)
      bfr[j] = *(const short8*)&Bs[(wn + j * 16 + r16) * 32 + quad * 8];
#pragma unroll
    for (int i = 0; i < 4; ++i)
#pragma unroll
      for (int j = 0; j < 4; ++j)
        acc[i][j] = __builtin_amdgcn_mfma_f32_16x16x32_bf16(af[i], bfr[j], acc[i][j], 0, 0, 0);
  }

  const int mb = mt * 128 + wm, nb = nt * 128 + wn;
#pragma unroll
  for (int j = 0; j < 4; ++j) {
    const int gcol = nb + j * 16 + r16;
    if (gcol >= Nstore) continue;
    const float bv = bias[gcol];
#pragma unroll
    for (int i = 0; i < 4; ++i) {
#pragma unroll
      for (int rg = 0; rg < 4; ++rg) {
        const int grow = mb + i * 16 + quad * 4 + rg;
        float v = acc[i][j][rg] + bv;
        if (MODE == 1) v = gelu_f(v);
        if (MODE == 2) v += pe[(grow & 127) * 288 + gcol];
        C[(long)grow * ldc + gcol] = f2bf(v);
      }
    }
  }
}

// ---------------------------------------------------------------------------
// Attention: one block per (b, head).  S=128, D_HEAD=41 (padded to 64).
// Scores kept in registers; softmax via shfl + 1KB LDS cross-wave combine;
// P (bf16) reuses the q/k LDS region.  Static LDS ~49 KB -> 3 blocks/CU.
// ---------------------------------------------------------------------------
__global__ __launch_bounds__(256)
void attn_kernel(const short* __restrict__ qg, const short* __restrict__ kg,
                 const short* __restrict__ vg, short* __restrict__ og,
                 const float* __restrict__ temp, const float* __restrict__ qscale,
                 int layer)
{
  __shared__ __align__(16) short qk[2 * 128 * 64];   // qs | ks, later Pb[128][128]
  __shared__ __align__(16) short vsT[64 * 128];
  __shared__ float red[2][2][64];                    // [rowhalf][colhalf][row&63]

  short* qs = qk;
  short* ks = qk + 128 * 64;
  short* Pb = qk;

  const int b = blockIdx.x, h = blockIdx.y;
  const int tid = threadIdx.x;
  const long base = ((long)b * 128) * 352 + h * 41;

  for (int idx = tid; idx < 128 * 64; idx += 256) {
    const int s = idx >> 6, d = idx & 63;
    short qv = 0, kv = 0, vv = 0;
    if (d < 41) {
      const long gi = base + (long)s * 352 + d;
      qv = qg[gi]; kv = kg[gi]; vv = vg[gi];
    }
    qs[idx] = qv; ks[idx] = kv; vsT[d * 128 + s] = vv;
  }
  __syncthreads();

  const int wave = tid >> 6, lane = tid & 63;
  const int quad = lane >> 4, r16 = lane & 15;
  const int wm = (wave >> 1) * 64, wn = (wave & 1) * 64;
  const int rh = wave >> 1, ch = wave & 1;
  const float invs = 1.0f / (6.4031242374328485f * temp[layer]); // 1/(sqrt(41)*temp)
  const float qsc  = qscale[layer * 8 + h];

  // ---- scores = Q K^T * invs (registers) ----
  floatx4 acc[4][4] = {};
#pragma unroll
  for (int kk = 0; kk < 2; ++kk) {
    const int k0 = kk * 32;
    short8 af[4], bfr[4];
#pragma unroll
    for (int i = 0; i < 4; ++i)
      af[i] = *(const short8*)&qs[(wm + i * 16 + r16) * 64 + k0 + quad * 8];
#pragma unroll
    for (int j = 0; j < 4; ++j)
      bfr[j] = *(const short8*)&ks[(wn + j * 16 + r16) * 64 + k0 + quad * 8];
#pragma unroll
    for (int i = 0; i < 4; ++i)
#pragma unroll
      for (int j = 0; j < 4; ++j)
        acc[i][j] = __builtin_amdgcn_mfma_f32_16x16x32_bf16(af[i], bfr[j], acc[i][j], 0, 0, 0);
  }
#pragma unroll
  for (int i = 0; i < 4; ++i)
#pragma unroll
    for (int j = 0; j < 4; ++j)
#pragma unroll
      for (int rg = 0; rg < 4; ++rg)
        acc[i][j][rg] *= invs;

  // ---- softmax: row max ----
  float rmax[4][4];
#pragma unroll
  for (int i = 0; i < 4; ++i)
#pragma unroll
    for (int rg = 0; rg < 4; ++rg) {
      float m = acc[i][0][rg];
#pragma unroll
      for (int j = 1; j < 4; ++j) m = fmaxf(m, acc[i][j][rg]);
      rmax[i][rg] = m;
    }
#pragma unroll
  for (int msk = 1; msk < 16; msk <<= 1)
#pragma unroll
    for (int i = 0; i < 4; ++i)
#pragma unroll
      for (int rg = 0; rg < 4; ++rg)
        rmax[i][rg] = fmaxf(rmax[i][rg], __shfl_xor(rmax[i][rg], msk));
  if (r16 == 0)
#pragma unroll
    for (int i = 0; i < 4; ++i)
#pragma unroll
      for (int rg = 0; rg < 4; ++rg)
        red[rh][ch][i * 16 + quad * 4 + rg] = rmax[i][rg];
  __syncthreads();
#pragma unroll
  for (int i = 0; i < 4; ++i)
#pragma unroll
    for (int rg = 0; rg < 4; ++rg) {
      const int r = i * 16 + quad * 4 + rg;
      rmax[i][rg] = fmaxf(red[rh][0][r], red[rh][1][r]);
    }

  // ---- exp + row sum ----
  float rsum[4][4] = {};
#pragma unroll
  for (int i = 0; i < 4; ++i)
#pragma unroll
    for (int j = 0; j < 4; ++j)
#pragma unroll
      for (int rg = 0; rg < 4; ++rg) {
        const float e = __expf(acc[i][j][rg] - rmax[i][rg]);
        acc[i][j][rg] = e;
        rsum[i][rg] += e;
      }
#pragma unroll
  for (int msk = 1; msk < 16; msk <<= 1)
#pragma unroll
    for (int i = 0; i < 4; ++i)
#pragma unroll
      for (int rg = 0; rg < 4; ++rg)
        rsum[i][rg] += __shfl_xor(rsum[i][rg], msk);
  __syncthreads();   // all reads of red(max) done before overwrite
  if (r16 == 0)
#pragma unroll
    for (int i = 0; i < 4; ++i)
#pragma unroll
      for (int rg = 0; rg < 4; ++rg)
        red[rh][ch][i * 16 + quad * 4 + rg] = rsum[i][rg];
  __syncthreads();
#pragma unroll
  for (int i = 0; i < 4; ++i)
#pragma unroll
    for (int rg = 0; rg < 4; ++rg) {
      const int r = i * 16 + quad * 4 + rg;
      rmax[i][rg] = qsc / (red[rh][0][r] + red[rh][1][r]);  // rowscale
    }

  // ---- write P bf16 (overwrites qs/ks region; all q/k reads are done) ----
#pragma unroll
  for (int i = 0; i < 4; ++i)
#pragma unroll
    for (int rg = 0; rg < 4; ++rg) {
      const int r = wm + i * 16 + quad * 4 + rg;
#pragma unroll
      for (int j = 0; j < 4; ++j)
        Pb[r * 128 + wn + j * 16 + r16] = f2bf(acc[i][j][rg] * rmax[i][rg]);
    }
  __syncthreads();

  // ---- O = P V ----
  const int om = (wave >> 1) * 64, on = (wave & 1) * 32;
  floatx4 oacc[4][2] = {};
#pragma unroll
  for (int kk = 0; kk < 4; ++kk) {
    const int k0 = kk * 32;
    short8 af[4], bfr[2];
#pragma unroll
    for (int i = 0; i < 4; ++i)
      af[i] = *(const short8*)&Pb[(om + i * 16 + r16) * 128 + k0 + quad * 8];
#pragma unroll
    for (int j = 0; j < 2; ++j)
      bfr[j] = *(const short8*)&vsT[(on + j * 16 + r16) * 128 + k0 + quad * 8];
#pragma unroll
    for (int i = 0; i < 4; ++i)
#pragma unroll
      for (int j = 0; j < 2; ++j)
        oacc[i][j] = __builtin_amdgcn_mfma_f32_16x16x32_bf16(af[i], bfr[j], oacc[i][j], 0, 0, 0);
  }
#pragma unroll
  for (int i = 0; i < 4; ++i)
#pragma unroll
    for (int j = 0; j < 2; ++j)
#pragma unroll
      for (int rg = 0; rg < 4; ++rg) {
        const int sq = om + i * 16 + quad * 4 + rg;
        const int d  = on + j * 16 + r16;
        if (d < 41) og[base + (long)sq * 352 + d] = f2bf(oacc[i][j][rg]);
      }

  // zero pad cols 328..351 of o (read as A of the Wo GEMM)
  if (h == 0) {
    for (int idx = tid; idx < 128 * 24; idx += 256) {
      const int s = idx / 24, c = idx % 24;
      og[((long)b * 128 + s) * 352 + 328 + c] = 0;
    }
  }
}

// ---------------------------------------------------------------------------
// LayerNorm: hb = LN(hb + skip * g) * w + b.  Wave per row, 4 rows/block.
// ---------------------------------------------------------------------------
__global__ __launch_bounds__(256)
void ln_kernel(short* __restrict__ hb, const short* __restrict__ g,
               const float* __restrict__ w, const float* __restrict__ bb,
               const float* __restrict__ skip_p, int layer, int use_skip)
{
  const int row  = blockIdx.x * 4 + (threadIdx.x >> 6);
  const int lane = threadIdx.x & 63;
  const float skipv = use_skip ? skip_p[layer] : 1.0f;
  const long ro = (long)row * 288;

  float x[5];
  float sum = 0.f, sum2 = 0.f;
#pragma unroll
  for (int t = 0; t < 5; ++t) {
    const int d = lane + t * 64;
    float v = 0.f;
    if (d < 288) v = bf2f(hb[ro + d]) + skipv * bf2f(g[ro + d]);
    x[t] = v;
    sum += v; sum2 += v * v;
  }
#pragma unroll
  for (int m = 1; m < 64; m <<= 1) {
    sum  += __shfl_xor(sum, m);
    sum2 += __shfl_xor(sum2, m);
  }
  const float mean = sum * (1.f / 288.f);
  const float var  = sum2 * (1.f / 288.f) - mean * mean;
  const float rstd = rsqrtf(var + 1e-5f);
#pragma unroll
  for (int t = 0; t < 5; ++t) {
    const int d = lane + t * 64;
    if (d < 288)
      hb[ro + d] = f2bf((x[t] - mean) * rstd * w[d] + bb[d]);
  }
}

// ---------------------------------------------------------------------------
// Pool over S + BN + GELU MLP head + uncertainty head.  Block per b.
// ---------------------------------------------------------------------------
__global__ __launch_bounds__(256)
void head_kernel(const short* __restrict__ hb, float* __restrict__ out,
                 const float* bn_w, const float* bn_b, const float* bn_mean, const float* bn_var,
                 const float* h1w, const float* h1b, const float* h2w, const float* h2b,
                 const float* h3w, const float* h3b,
                 const float* u1w, const float* u1b, const float* u2w, const float* u2b)
{
  __shared__ float pooled[288], z[288], z1[144], z2[72], uu[72];
  const int b = blockIdx.x, tid = threadIdx.x;

  float a0 = 0.f, a1 = 0.f;
  for (int s = 0; s < 128; ++s) {
    const long ro = ((long)b * 128 + s) * 288;
    a0 += bf2f(hb[ro + tid]);
    if (tid < 32) a1 += bf2f(hb[ro + 256 + tid]);
  }
  pooled[tid] = a0 * (1.f / 128.f);
  if (tid < 32) pooled[256 + tid] = a1 * (1.f / 128.f);
  __syncthreads();

  for (int d = tid; d < 288; d += 256) {
    const float p = pooled[d];
    z[d] = gelu_f((p - bn_mean[d]) * rsqrtf(bn_var[d] + 1e-5f) * bn_w[d] + bn_b[d]);
  }
  __syncthreads();

  if (tid < 144) {
    float s = h1b[tid];
    for (int k = 0; k < 288; ++k) s += z[k] * h1w[tid * 288 + k];
    z1[tid] = gelu_f(s);
  } else if (tid < 216) {
    const int t = tid - 144;
    float s = u1b[t];
    for (int k = 0; k < 288; ++k) s += pooled[k] * u1w[t * 288 + k];
    uu[t] = fmaxf(s, 0.f);
  }
  __syncthreads();

  if (tid < 72) {
    float s = h2b[tid];
    for (int k = 0; k < 144; ++k) s += z1[k] * h2w[tid * 144 + k];
    z2[tid] = gelu_f(s);
  }
  __syncthreads();

  if (tid == 0) {
    float s = h3b[0];
    for (int k = 0; k < 72; ++k) s += z2[k] * h3w[k];
    out[b] = s;
  }
  if (tid == 64) {
    float s = u2b[0];
    for (int k = 0; k < 72; ++k) s += uu[k] * u2w[k];
    out[1024 + b] = (s > 20.f) ? s : log1pf(__expf(s));
  }
}

// ---------------------------------------------------------------------------
// Conversion / padding kernels (re-run every call; ws is re-poisoned).
// ---------------------------------------------------------------------------
__global__ void conv_w_kernel(const float* __restrict__ src, short* __restrict__ dst,
                              int N, int K, int Npad, int Kpad, int total)
{
  const int i = blockIdx.x * 256 + threadIdx.x;
  if (i >= total) return;
  const int kk = i % Kpad;
  const int t  = i / Kpad;
  const int n  = t % Npad;
  const int l  = t / Npad;
  const float v = (n < N && kk < K) ? src[((long)l * N + n) * K + kk] : 0.f;
  dst[i] = f2bf(v);
}

__global__ void conv_b_kernel(const float* __restrict__ src, float* __restrict__ dst,
                              int N, int Npad, int total)
{
  const int i = blockIdx.x * 256 + threadIdx.x;
  if (i >= total) return;
  const int n = i % Npad, l = i / Npad;
  dst[i] = (n < N) ? src[l * N + n] : 0.f;
}

__global__ void conv_x_kernel(const float* __restrict__ x, short* __restrict__ xb, int total)
{
  const int i = blockIdx.x * 256 + threadIdx.x;
  if (i >= total) return;
  const int c = i % 96;
  const int r = i / 96;
  xb[i] = f2bf((c < 83) ? x[(long)r * 83 + c] : 0.f);
}

__global__ void pe_kernel(const float* __restrict__ phase, float* __restrict__ pe_mod)
{
  const int i = blockIdx.x * 256 + threadIdx.x;
  if (i >= 128 * 288) return;
  const int d = i % 288, s = i / 288;
  const int pair = d >> 1;
  const float divv = expf((float)(2 * pair) * (-9.210340371976184f / 288.f));
  const float arg = (float)s * divv;
  const float v = (d & 1) ? cosf(arg) : sinf(arg);
  pe_mod[i] = v * cosf(phase[d]);
}

// ---------------------------------------------------------------------------
extern "C" void kernel_launch(void* const* d_in, const int* in_sizes, int n_in,
                              void* d_out, int out_size, void* d_ws, size_t ws_size,
                              hipStream_t stream)
{
  (void)in_sizes; (void)n_in; (void)out_size;

  const float* x     = (const float*)d_in[0];
  const float* Wp    = (const float*)d_in[1];
  const float* bp    = (const float*)d_in[2];
  const float* phase = (const float*)d_in[3];
  const float* Wq    = (const float*)d_in[4];
  const float* bq    = (const float*)d_in[5];
  const float* Wk    = (const float*)d_in[6];
  const float* bk    = (const float*)d_in[7];
  const float* Wv    = (const float*)d_in[8];
  const float* bv    = (const float*)d_in[9];
  const float* Wo    = (const float*)d_in[10];
  const float* bo    = (const float*)d_in[11];
  const float* temp  = (const float*)d_in[12];
  const float* qscale= (const float*)d_in[13];
  const float* Wf1   = (const float*)d_in[14];
  const float* bf1   = (const float*)d_in[15];
  const float* Wf2   = (const float*)d_in[16];
  const float* bf2   = (const float*)d_in[17];
  const float* n1w   = (const float*)d_in[18];
  const float* n1b   = (const float*)d_in[19];
  const float* n2w   = (const float*)d_in[20];
  const float* n2b   = (const float*)d_in[21];
  const float* skip  = (const float*)d_in[22];
  const float* bn_w  = (const float*)d_in[23];
  const float* bn_b  = (const float*)d_in[24];
  const float* bn_mean=(const float*)d_in[25];
  const float* bn_var= (const float*)d_in[26];
  const float* h1w   = (const float*)d_in[27];
  const float* h1b   = (const float*)d_in[28];
  const float* h2w   = (const float*)d_in[29];
  const float* h2b   = (const float*)d_in[30];
  const float* h3w   = (const float*)d_in[31];
  const float* h3b   = (const float*)d_in[32];
  const float* u1w   = (const float*)d_in[33];
  const float* u1b   = (const float*)d_in[34];
  const float* u2w   = (const float*)d_in[35];
  const float* u2b   = (const float*)d_in[36];

  char* ws = (char*)d_ws;
  size_t off = 0;
  auto alloc = [&](size_t n) -> char* {
    off = (off + 255) & ~(size_t)255;
    char* p = ws + off;
    off += n;
    return p;
  };

  const long M = 131072;

  // ---- fixed allocations ----
  short* h_bf  = (short*)alloc((size_t)M * 288 * 2);
  float* pe_mod= (float*)alloc(128 * 288 * 4);

  short* Wp_b  = (short*)alloc((size_t)384 * 96 * 2);
  short* Wq_b  = (short*)alloc((size_t)4 * 384 * 288 * 2);
  short* Wk_b  = (short*)alloc((size_t)4 * 384 * 288 * 2);
  short* Wv_b  = (short*)alloc((size_t)4 * 384 * 288 * 2);
  short* Wo_b  = (short*)alloc((size_t)4 * 384 * 352 * 2);
  short* Wf1_b = (short*)alloc((size_t)4 * 1408 * 288 * 2);
  short* Wf2_b = (short*)alloc((size_t)4 * 384 * 1344 * 2);

  float* bp_p  = (float*)alloc((size_t)384 * 4);
  float* bq_p  = (float*)alloc((size_t)4 * 384 * 4);
  float* bk_p  = (float*)alloc((size_t)4 * 384 * 4);
  float* bv_p  = (float*)alloc((size_t)4 * 384 * 4);
  float* bo_p  = (float*)alloc((size_t)4 * 384 * 4);
  float* bf1_p = (float*)alloc((size_t)4 * 1408 * 4);
  float* bf2_p = (float*)alloc((size_t)4 * 384 * 4);

  // ---- adaptive batch chunking: per-token scratch = Mc*3392 bytes ----
  // (R1 = 4*Mc*352*2 holding q|k|v|o, aliased by f (Mc*1344*2) and x (Mc*96*2);
  //  g = Mc*288*2)
  const size_t fixed = off;
  int NC = 1;
  while (NC < 8 && fixed + (size_t)(M / NC) * 3392 + (1u << 20) > ws_size) NC <<= 1;
  const long Mc = M / NC;

  char*  R1   = alloc((size_t)4 * Mc * 352 * 2);
  short* g_bf = (short*)alloc((size_t)Mc * 288 * 2);

  short* q_bf = (short*)R1;
  short* k_bf = q_bf + (size_t)Mc * 352;
  short* v_bf = k_bf + (size_t)Mc * 352;
  short* o_bf = v_bf + (size_t)Mc * 352;
  short* f_bf = (short*)R1;   // aliases q..o (dead at FFN time)
  short* x_bfc= (short*)R1;   // aliases too (dead after input GEMM)

  const dim3 blk(256);

  // ---- weight/bias conversion + positional encoding (chunk-independent) ----
  auto conv_w = [&](const float* s, short* d, int N, int K, int Np, int Kp, int L) {
    const int total = L * Np * Kp;
    conv_w_kernel<<<dim3((total + 255) / 256), blk, 0, stream>>>(s, d, N, K, Np, Kp, total);
  };
  auto conv_b = [&](const float* s, float* d, int N, int Np, int L) {
    const int total = L * Np;
    conv_b_kernel<<<dim3((total + 255) / 256), blk, 0, stream>>>(s, d, N, Np, total);
  };
  conv_w(Wp,  Wp_b,  288,   83, 384,   96, 1);
  conv_w(Wq,  Wq_b,  328,  288, 384,  288, 4);
  conv_w(Wk,  Wk_b,  328,  288, 384,  288, 4);
  conv_w(Wv,  Wv_b,  328,  288, 384,  288, 4);
  conv_w(Wo,  Wo_b,  288,  328, 384,  352, 4);
  conv_w(Wf1, Wf1_b, 1315, 288, 1408, 288, 4);
  conv_w(Wf2, Wf2_b, 288, 1315, 384, 1344, 4);
  conv_b(bp,  bp_p,  288,  384, 1);
  conv_b(bq,  bq_p,  328,  384, 4);
  conv_b(bk,  bk_p,  328,  384, 4);
  conv_b(bv,  bv_p,  328,  384, 4);
  conv_b(bo,  bo_p,  288,  384, 4);
  conv_b(bf1, bf1_p, 1315, 1408, 4);
  conv_b(bf2, bf2_p, 288,  384, 4);
  pe_kernel<<<dim3((128 * 288 + 255) / 256), blk, 0, stream>>>(phase, pe_mod);

  auto gemm = [&](int mode, const short* A, const short* Bmat, const float* bias,
                  short* C, const float* pe, int K, int ld, int ldc,
                  int Nstore, int NT, long Mrows) {
    const dim3 grid((unsigned)(Mrows / 128), NT);
    switch (mode) {
      case 0: gemm_kernel<0><<<grid, blk, 0, stream>>>(A, Bmat, bias, C, pe, K, ld, ld, ldc, Nstore); break;
      case 1: gemm_kernel<1><<<grid, blk, 0, stream>>>(A, Bmat, bias, C, pe, K, ld, ld, ldc, Nstore); break;
      default: gemm_kernel<2><<<grid, blk, 0, stream>>>(A, Bmat, bias, C, pe, K, ld, ld, ldc, Nstore); break;
    }
  };

  for (int c = 0; c < NC; ++c) {
    const float* x_c = x + (size_t)c * Mc * 83;
    short* h_c = h_bf + (size_t)c * Mc * 288;

    const int xtot = (int)(Mc * 96);
    conv_x_kernel<<<dim3((xtot + 255) / 256), blk, 0, stream>>>(x_c, x_bfc, xtot);

    // input projection + positional encoding
    gemm(2, x_bfc, Wp_b, bp_p, h_c, pe_mod, 96, 96, 288, 288, 3, Mc);

    for (int l = 0; l < 4; ++l) {
      const short* Wq_l  = Wq_b  + (size_t)l * 384 * 288;
      const short* Wk_l  = Wk_b  + (size_t)l * 384 * 288;
      const short* Wv_l  = Wv_b  + (size_t)l * 384 * 288;
      const short* Wo_l  = Wo_b  + (size_t)l * 384 * 352;
      const short* Wf1_l = Wf1_b + (size_t)l * 1408 * 288;
      const short* Wf2_l = Wf2_b + (size_t)l * 384 * 1344;

      gemm(0, h_c, Wq_l, bq_p + l * 384, q_bf, nullptr, 288, 288, 352, 352, 3, Mc);
      gemm(0, h_c, Wk_l, bk_p + l * 384, k_bf, nullptr, 288, 288, 352, 352, 3, Mc);
      gemm(0, h_c, Wv_l, bv_p + l * 384, v_bf, nullptr, 288, 288, 352, 352, 3, Mc);

      attn_kernel<<<dim3((unsigned)(Mc / 128), 8), blk, 0, stream>>>(
          q_bf, k_bf, v_bf, o_bf, temp, qscale, l);

      gemm(0, o_bf, Wo_l, bo_p + l * 384, g_bf, nullptr, 352, 352, 288, 288, 3, Mc);
      ln_kernel<<<dim3((unsigned)(Mc / 4)), blk, 0, stream>>>(
          h_c, g_bf, n1w + l * 288, n1b + l * 288, skip, l, 1);

      gemm(1, h_c, Wf1_l, bf1_p + l * 1408, f_bf, nullptr, 288, 288, 1344, 1344, 11, Mc);
      gemm(0, f_bf, Wf2_l, bf2_p + l * 384, g_bf, nullptr, 1344, 1344, 288, 288, 3, Mc);
      ln_kernel<<<dim3((unsigned)(Mc / 4)), blk, 0, stream>>>(
          h_c, g_bf, n2w + l * 288, n2b + l * 288, skip, l, 0);
    }
  }

  head_kernel<<<dim3(1024), blk, 0, stream>>>(h_bf, (float*)d_out,
      bn_w, bn_b, bn_mean, bn_var,
      h1w, h1b, h2w, h2b, h3w, h3b,
      u1w, u1b, u2w, u2b);
}

// Round 4
// 4240.108 us; speedup vs baseline: 1.2356x; 1.2356x over previous
//
#include <hip/hip_runtime.h>
#include <cstdint>

typedef __attribute__((ext_vector_type(8))) short short8;
typedef __attribute__((ext_vector_type(4))) float floatx4;

#define DEV __device__ __forceinline__

DEV short f2bf(float f) {
  unsigned u = __builtin_bit_cast(unsigned, f);
  u += 0x7fffu + ((u >> 16) & 1u);
  return (short)(u >> 16);
}
DEV float bf2f(short s) {
  unsigned u = ((unsigned)(unsigned short)s) << 16;
  return __builtin_bit_cast(float, u);
}
DEV float gelu_exact(float x) {
  return 0.5f * x * (1.0f + erff(x * 0.70710678118654752f));
}
// tanh-approx gelu via sigmoid identity: 0.5(1+tanh(t)) == sigmoid(2t); |err|<~5e-4
DEV float gelu_fast(float x) {
  const float t2 = 1.5957691216057308f * (x + 0.044715f * x * x * x);
  return x / (1.0f + __expf(-t2));
}
DEV void gload16(const void* g, void* l) {
  __builtin_amdgcn_global_load_lds((const __attribute__((address_space(1))) void*)g,
                                   (__attribute__((address_space(3))) void*)l,
                                   16, 0, 0);
}

// ---------------------------------------------------------------------------
// 128x128-tile bf16 MFMA GEMM.  C[M,N] = A[M,K] * Bw[N,K]^T + bias.
// 1-D grid (MT*NT, XCD-swizzled: nt fastest within an XCD for A-tile L2 reuse).
// LDS staging XOR-swizzled (chunk ^= (row>>1)&3) -> conflict-free b128 reads.
// MODE 0: C = v + bias
// MODE 1: C = gelu_fast(v + bias)
// MODE 2: C = v + bias + pe[(row&127)*288 + col]
// MODE 3: fused QKV scatter: col -> sec(=col/384), head(=cin/41), d; dest
//         Cq + ((sec*8+head)*McA + row)*48 + d   (cin<328 only)
// ---------------------------------------------------------------------------
template<int MODE>
__global__ __launch_bounds__(256)
void gemm_kernel(const short* __restrict__ A, const short* __restrict__ Bw,
                 const float* __restrict__ bias, short* __restrict__ C,
                 const float* __restrict__ pe, short* __restrict__ Cq,
                 int K, int lda, int ldb, int ldc, int Nstore, int NT, int McA)
{
  __shared__ __align__(16) short As[128 * 32];
  __shared__ __align__(16) short Bs[128 * 32];
  const int tid  = threadIdx.x;
  const int wave = tid >> 6, lane = tid & 63;
  const int quad = lane >> 4, r16 = lane & 15;
  const int per = gridDim.x >> 3;                    // grid always %8==0
  const int gti = (blockIdx.x & 7) * per + (blockIdx.x >> 3);
  const int mt = gti / NT, nt = gti - mt * NT;
  const int wm = (wave >> 1) * 64, wn = (wave & 1) * 64;

  const long Abase = (long)mt * 128 * lda;
  const long Bbase = (long)nt * 128 * ldb;

  const int row0 = tid >> 2,         cc0 = (tid & 3) ^ ((row0 >> 1) & 3);
  const int row1 = (256 + tid) >> 2, cc1 = ((256 + tid) & 3) ^ ((row1 >> 1) & 3);

  floatx4 acc[4][4] = {};

  for (int k0 = 0; k0 < K; k0 += 32) {
    __syncthreads();
    gload16(A  + Abase + (long)row0 * lda + k0 + cc0 * 8, &As[(0 * 256 + wave * 64) * 8]);
    gload16(A  + Abase + (long)row1 * lda + k0 + cc1 * 8, &As[(1 * 256 + wave * 64) * 8]);
    gload16(Bw + Bbase + (long)row0 * ldb + k0 + cc0 * 8, &Bs[(0 * 256 + wave * 64) * 8]);
    gload16(Bw + Bbase + (long)row1 * ldb + k0 + cc1 * 8, &Bs[(1 * 256 + wave * 64) * 8]);
    __syncthreads();

    short8 af[4], bfr[4];
#pragma unroll
    for (int i = 0; i < 4; ++i) {
      const int R = wm + i * 16 + r16;
      af[i] = *(const short8*)&As[R * 32 + (quad ^ ((R >> 1) & 3)) * 8];
    }
#pragma unroll
    for (int j = 0; j < 4; ++j) {
      const int R = wn + j * 16 + r16;
      bfr[j] = *(const short8*)&Bs[R * 32 + (quad ^ ((R >> 1) & 3)) * 8];
    }
#pragma unroll
    for (int i = 0; i < 4; ++i)
#pragma unroll
      for (int j = 0; j < 4; ++j)
        acc[i][j] = __builtin_amdgcn_mfma_f32_16x16x32_bf16(af[i], bfr[j], acc[i][j], 0, 0, 0);
  }

  const int mb = mt * 128 + wm, nb = nt * 128 + wn;
#pragma unroll
  for (int j = 0; j < 4; ++j) {
    const int gcol = nb + j * 16 + r16;
    if (MODE != 3 && gcol >= Nstore) continue;
    int sec = 0, cin = 0, head = 0, d = 0;
    if (MODE == 3) {
      sec = gcol / 384;
      cin = gcol - sec * 384;
      if (cin >= 328) continue;
      head = cin / 41;
      d = cin - head * 41;
    }
    const float bv = bias[gcol];
#pragma unroll
    for (int i = 0; i < 4; ++i) {
#pragma unroll
      for (int rg = 0; rg < 4; ++rg) {
        const int grow = mb + i * 16 + quad * 4 + rg;
        float v = acc[i][j][rg] + bv;
        if (MODE == 0) {
          C[(long)grow * ldc + gcol] = f2bf(v);
        } else if (MODE == 1) {
          C[(long)grow * ldc + gcol] = f2bf(gelu_fast(v));
        } else if (MODE == 2) {
          v += pe[(grow & 127) * 288 + gcol];
          C[(long)grow * ldc + gcol] = f2bf(v);
        } else {
          Cq[((long)(sec * 8 + head) * McA + grow) * 48 + d] = f2bf(v);
        }
      }
    }
  }
}

// ---------------------------------------------------------------------------
// Attention: one block per (b, head).  S=128, D_HEAD=41 (padded to 48 in
// global, 64 in LDS).  qkv layout: [sec][head][Mc][48] bf16.
// LDS: qs/ks stride 72 (K-dim = 64-padded d); vsT stride 136 (K-dim = s = 128!);
// Pb stride 136.  All strides multiple of 8 shorts for aligned b128.
// ---------------------------------------------------------------------------
__global__ __launch_bounds__(256)
void attn_kernel(const short* __restrict__ qkv, short* __restrict__ og,
                 const float* __restrict__ temp, const float* __restrict__ qscale,
                 int layer, long Mc)
{
  __shared__ __align__(16) short qk[2 * 128 * 72];   // qs|ks, later Pb[128][136]
  __shared__ __align__(16) short vsT[64 * 136];      // [d][s], stride 136 >= 128
  __shared__ float red[2][2][64];

  short* qs = qk;
  short* ks = qk + 128 * 72;
  short* Pb = qk;

  const int b = blockIdx.x, h = blockIdx.y;
  const int tid = threadIdx.x;
  const long secs = (long)8 * Mc * 48;
  const long rbase = ((long)h * Mc + (long)b * 128) * 48;
  const short* qg = qkv + rbase;
  const short* kg = qkv + secs + rbase;
  const short* vg = qkv + 2 * secs + rbase;

  // q,k: rows of 8 chunks (dc 0..5 real, 5 tail-zeroed, 6..7 zero)
  for (int c = tid; c < 1024; c += 256) {
    const int s = c >> 3, dc = c & 7;
    short8 tq, tk;
#pragma unroll
    for (int j = 0; j < 8; ++j) { tq[j] = 0; tk[j] = 0; }
    if (dc < 6) {
      tq = *(const short8*)(qg + (long)s * 48 + dc * 8);
      tk = *(const short8*)(kg + (long)s * 48 + dc * 8);
      if (dc == 5) {
#pragma unroll
        for (int j = 1; j < 8; ++j) { tq[j] = 0; tk[j] = 0; }
      }
    }
    *(short8*)&qs[s * 72 + dc * 8] = tq;
    *(short8*)&ks[s * 72 + dc * 8] = tk;
  }
  // v transposed into vsT[d][s] (stride 136)
  for (int c = tid; c < 768; c += 256) {
    const int s = c / 6, dc = c - (c / 6) * 6;
    short8 tv = *(const short8*)(vg + (long)s * 48 + dc * 8);
    if (dc == 5) {
#pragma unroll
      for (int j = 1; j < 8; ++j) tv[j] = 0;
    }
#pragma unroll
    for (int j = 0; j < 8; ++j) vsT[(dc * 8 + j) * 136 + s] = tv[j];
  }
  __syncthreads();

  const int wave = tid >> 6, lane = tid & 63;
  const int quad = lane >> 4, r16 = lane & 15;
  const int wm = (wave >> 1) * 64, wn = (wave & 1) * 64;
  const int rh = wave >> 1, ch = wave & 1;
  const float invs = 1.0f / (6.4031242374328485f * temp[layer]); // 1/(sqrt(41)*temp)
  const float qsc  = qscale[layer * 8 + h];

  // ---- scores = Q K^T * invs (registers) ----
  floatx4 acc[4][4] = {};
#pragma unroll
  for (int kk = 0; kk < 2; ++kk) {
    const int k0 = kk * 32;
    short8 af[4], bfr[4];
#pragma unroll
    for (int i = 0; i < 4; ++i)
      af[i] = *(const short8*)&qs[(wm + i * 16 + r16) * 72 + k0 + quad * 8];
#pragma unroll
    for (int j = 0; j < 4; ++j)
      bfr[j] = *(const short8*)&ks[(wn + j * 16 + r16) * 72 + k0 + quad * 8];
#pragma unroll
    for (int i = 0; i < 4; ++i)
#pragma unroll
      for (int j = 0; j < 4; ++j)
        acc[i][j] = __builtin_amdgcn_mfma_f32_16x16x32_bf16(af[i], bfr[j], acc[i][j], 0, 0, 0);
  }
#pragma unroll
  for (int i = 0; i < 4; ++i)
#pragma unroll
    for (int j = 0; j < 4; ++j)
#pragma unroll
      for (int rg = 0; rg < 4; ++rg)
        acc[i][j][rg] *= invs;

  // ---- softmax row max ----
  float rmax[4][4];
#pragma unroll
  for (int i = 0; i < 4; ++i)
#pragma unroll
    for (int rg = 0; rg < 4; ++rg) {
      float m = acc[i][0][rg];
#pragma unroll
      for (int j = 1; j < 4; ++j) m = fmaxf(m, acc[i][j][rg]);
      rmax[i][rg] = m;
    }
#pragma unroll
  for (int msk = 1; msk < 16; msk <<= 1)
#pragma unroll
    for (int i = 0; i < 4; ++i)
#pragma unroll
      for (int rg = 0; rg < 4; ++rg)
        rmax[i][rg] = fmaxf(rmax[i][rg], __shfl_xor(rmax[i][rg], msk));
  if (r16 == 0)
#pragma unroll
    for (int i = 0; i < 4; ++i)
#pragma unroll
      for (int rg = 0; rg < 4; ++rg)
        red[rh][ch][i * 16 + quad * 4 + rg] = rmax[i][rg];
  __syncthreads();
#pragma unroll
  for (int i = 0; i < 4; ++i)
#pragma unroll
    for (int rg = 0; rg < 4; ++rg) {
      const int r = i * 16 + quad * 4 + rg;
      rmax[i][rg] = fmaxf(red[rh][0][r], red[rh][1][r]);
    }

  // ---- exp + row sum ----
  float rsum[4][4] = {};
#pragma unroll
  for (int i = 0; i < 4; ++i)
#pragma unroll
    for (int j = 0; j < 4; ++j)
#pragma unroll
      for (int rg = 0; rg < 4; ++rg) {
        const float e = __expf(acc[i][j][rg] - rmax[i][rg]);
        acc[i][j][rg] = e;
        rsum[i][rg] += e;
      }
#pragma unroll
  for (int msk = 1; msk < 16; msk <<= 1)
#pragma unroll
    for (int i = 0; i < 4; ++i)
#pragma unroll
      for (int rg = 0; rg < 4; ++rg)
        rsum[i][rg] += __shfl_xor(rsum[i][rg], msk);
  __syncthreads();
  if (r16 == 0)
#pragma unroll
    for (int i = 0; i < 4; ++i)
#pragma unroll
      for (int rg = 0; rg < 4; ++rg)
        red[rh][ch][i * 16 + quad * 4 + rg] = rsum[i][rg];
  __syncthreads();
#pragma unroll
  for (int i = 0; i < 4; ++i)
#pragma unroll
    for (int rg = 0; rg < 4; ++rg) {
      const int r = i * 16 + quad * 4 + rg;
      rmax[i][rg] = qsc / (red[rh][0][r] + red[rh][1][r]);  // rowscale
    }

  // ---- write P (bf16, stride 136) over qs/ks ----
#pragma unroll
  for (int i = 0; i < 4; ++i)
#pragma unroll
    for (int rg = 0; rg < 4; ++rg) {
      const int r = wm + i * 16 + quad * 4 + rg;
#pragma unroll
      for (int j = 0; j < 4; ++j)
        Pb[r * 136 + wn + j * 16 + r16] = f2bf(acc[i][j][rg] * rmax[i][rg]);
    }
  __syncthreads();

  // ---- O = P V ----
  const int om = (wave >> 1) * 64, on = (wave & 1) * 32;
  floatx4 oacc[4][2] = {};
#pragma unroll
  for (int kk = 0; kk < 4; ++kk) {
    const int k0 = kk * 32;
    short8 af[4], bfr[2];
#pragma unroll
    for (int i = 0; i < 4; ++i)
      af[i] = *(const short8*)&Pb[(om + i * 16 + r16) * 136 + k0 + quad * 8];
#pragma unroll
    for (int j = 0; j < 2; ++j)
      bfr[j] = *(const short8*)&vsT[(on + j * 16 + r16) * 136 + k0 + quad * 8];
#pragma unroll
    for (int i = 0; i < 4; ++i)
#pragma unroll
      for (int j = 0; j < 2; ++j)
        oacc[i][j] = __builtin_amdgcn_mfma_f32_16x16x32_bf16(af[i], bfr[j], oacc[i][j], 0, 0, 0);
  }
  const long obase = ((long)b * 128) * 352 + h * 41;
#pragma unroll
  for (int i = 0; i < 4; ++i)
#pragma unroll
    for (int j = 0; j < 2; ++j)
#pragma unroll
      for (int rg = 0; rg < 4; ++rg) {
        const int sq = om + i * 16 + quad * 4 + rg;
        const int d  = on + j * 16 + r16;
        if (d < 41) og[obase + (long)sq * 352 + d] = f2bf(oacc[i][j][rg]);
      }

  // zero pad cols 328..351 of o (read as A by the Wo GEMM)
  if (h == 0) {
    for (int idx = tid; idx < 128 * 24; idx += 256) {
      const int s = idx / 24, c = idx - (idx / 24) * 24;
      og[((long)b * 128 + s) * 352 + 328 + c] = 0;
    }
  }
}

// ---------------------------------------------------------------------------
// LayerNorm: hb = LN(hb + skip * g) * w + b.  Wave per row (36 active lanes,
// short8 vector loads/stores), 4 rows/block.
// ---------------------------------------------------------------------------
__global__ __launch_bounds__(256)
void ln_kernel(short* __restrict__ hb, const short* __restrict__ g,
               const float* __restrict__ w, const float* __restrict__ bb,
               const float* __restrict__ skip_p, int layer, int use_skip)
{
  const int row  = blockIdx.x * 4 + (threadIdx.x >> 6);
  const int lane = threadIdx.x & 63;
  const float skipv = use_skip ? skip_p[layer] : 1.0f;
  const long base = (long)row * 288 + lane * 8;

  float xv[8];
  float sum = 0.f, sum2 = 0.f;
  if (lane < 36) {
    const short8 hv = *(const short8*)(hb + base);
    const short8 gv = *(const short8*)(g + base);
#pragma unroll
    for (int j = 0; j < 8; ++j) {
      const float v = bf2f(hv[j]) + skipv * bf2f(gv[j]);
      xv[j] = v;
      sum += v; sum2 += v * v;
    }
  } else {
#pragma unroll
    for (int j = 0; j < 8; ++j) xv[j] = 0.f;
  }
#pragma unroll
  for (int m = 1; m < 64; m <<= 1) {
    sum  += __shfl_xor(sum, m);
    sum2 += __shfl_xor(sum2, m);
  }
  const float mean = sum * (1.f / 288.f);
  const float var  = sum2 * (1.f / 288.f) - mean * mean;
  const float rstd = rsqrtf(var + 1e-5f);
  if (lane < 36) {
    short8 o;
#pragma unroll
    for (int j = 0; j < 8; ++j)
      o[j] = f2bf((xv[j] - mean) * rstd * w[lane * 8 + j] + bb[lane * 8 + j]);
    *(short8*)(hb + base) = o;
  }
}

// ---------------------------------------------------------------------------
// Pool over S + BN + GELU MLP head + uncertainty head.  Block per b.
// ---------------------------------------------------------------------------
__global__ __launch_bounds__(256)
void head_kernel(const short* __restrict__ hb, float* __restrict__ out,
                 const float* bn_w, const float* bn_b, const float* bn_mean, const float* bn_var,
                 const float* h1w, const float* h1b, const float* h2w, const float* h2b,
                 const float* h3w, const float* h3b,
                 const float* u1w, const float* u1b, const float* u2w, const float* u2b)
{
  __shared__ float pooled[288], z[288], z1[144], z2[72], uu[72];
  const int b = blockIdx.x, tid = threadIdx.x;

  float a0 = 0.f, a1 = 0.f;
  for (int s = 0; s < 128; ++s) {
    const long ro = ((long)b * 128 + s) * 288;
    a0 += bf2f(hb[ro + tid]);
    if (tid < 32) a1 += bf2f(hb[ro + 256 + tid]);
  }
  pooled[tid] = a0 * (1.f / 128.f);
  if (tid < 32) pooled[256 + tid] = a1 * (1.f / 128.f);
  __syncthreads();

  for (int d = tid; d < 288; d += 256) {
    const float p = pooled[d];
    z[d] = gelu_exact((p - bn_mean[d]) * rsqrtf(bn_var[d] + 1e-5f) * bn_w[d] + bn_b[d]);
  }
  __syncthreads();

  if (tid < 144) {
    float s = h1b[tid];
    for (int k = 0; k < 288; ++k) s += z[k] * h1w[tid * 288 + k];
    z1[tid] = gelu_exact(s);
  } else if (tid < 216) {
    const int t = tid - 144;
    float s = u1b[t];
    for (int k = 0; k < 288; ++k) s += pooled[k] * u1w[t * 288 + k];
    uu[t] = fmaxf(s, 0.f);
  }
  __syncthreads();

  if (tid < 72) {
    float s = h2b[tid];
    for (int k = 0; k < 144; ++k) s += z1[k] * h2w[tid * 144 + k];
    z2[tid] = gelu_exact(s);
  }
  __syncthreads();

  if (tid == 0) {
    float s = h3b[0];
    for (int k = 0; k < 72; ++k) s += z2[k] * h3w[k];
    out[b] = s;
  }
  if (tid == 64) {
    float s = u2b[0];
    for (int k = 0; k < 72; ++k) s += uu[k] * u2w[k];
    out[1024 + b] = (s > 20.f) ? s : log1pf(__expf(s));
  }
}

// ---------------------------------------------------------------------------
// Conversion / padding kernels
// ---------------------------------------------------------------------------
__global__ void conv_w_kernel(const float* __restrict__ src, short* __restrict__ dst,
                              int N, int K, int Npad, int Kpad, int total)
{
  const int i = blockIdx.x * 256 + threadIdx.x;
  if (i >= total) return;
  const int kk = i % Kpad;
  const int t  = i / Kpad;
  const int n  = t % Npad;
  const int l  = t / Npad;
  const float v = (n < N && kk < K) ? src[((long)l * N + n) * K + kk] : 0.f;
  dst[i] = f2bf(v);
}

__global__ void conv_b_kernel(const float* __restrict__ src, float* __restrict__ dst,
                              int N, int Npad, int total)
{
  const int i = blockIdx.x * 256 + threadIdx.x;
  if (i >= total) return;
  const int n = i % Npad, l = i / Npad;
  dst[i] = (n < N) ? src[l * N + n] : 0.f;
}

// fused QKV weight: dst [4][1152][288]; rows r: sec=r/384, rin=r%384 (<328 real)
__global__ void conv_wqkv_kernel(const float* __restrict__ Wq, const float* __restrict__ Wk,
                                 const float* __restrict__ Wv, short* __restrict__ dst)
{
  const int i = blockIdx.x * 256 + threadIdx.x;
  if (i >= 4 * 1152 * 288) return;
  const int kk = i % 288;
  const int t  = i / 288;
  const int r  = t % 1152;
  const int l  = t / 1152;
  const int sec = r / 384, rin = r - sec * 384;
  float v = 0.f;
  if (rin < 328) {
    const float* W = (sec == 0) ? Wq : (sec == 1) ? Wk : Wv;
    v = W[((long)l * 328 + rin) * 288 + kk];
  }
  dst[i] = f2bf(v);
}

__global__ void conv_bqkv_kernel(const float* __restrict__ bq, const float* __restrict__ bk,
                                 const float* __restrict__ bv, float* __restrict__ dst)
{
  const int i = blockIdx.x * 256 + threadIdx.x;
  if (i >= 4 * 1152) return;
  const int r = i % 1152, l = i / 1152;
  const int sec = r / 384, rin = r - sec * 384;
  float v = 0.f;
  if (rin < 328) {
    const float* b = (sec == 0) ? bq : (sec == 1) ? bk : bv;
    v = b[l * 328 + rin];
  }
  dst[i] = v;
}

__global__ void conv_x_kernel(const float* __restrict__ x, short* __restrict__ xb, int total)
{
  const int i = blockIdx.x * 256 + threadIdx.x;
  if (i >= total) return;
  const int c = i % 96;
  const int r = i / 96;
  xb[i] = f2bf((c < 83) ? x[(long)r * 83 + c] : 0.f);
}

__global__ void pe_kernel(const float* __restrict__ phase, float* __restrict__ pe_mod)
{
  const int i = blockIdx.x * 256 + threadIdx.x;
  if (i >= 128 * 288) return;
  const int d = i % 288, s = i / 288;
  const int pair = d >> 1;
  const float divv = expf((float)(2 * pair) * (-9.210340371976184f / 288.f));
  const float arg = (float)s * divv;
  const float v = (d & 1) ? cosf(arg) : sinf(arg);
  pe_mod[i] = v * cosf(phase[d]);
}

// ---------------------------------------------------------------------------
extern "C" void kernel_launch(void* const* d_in, const int* in_sizes, int n_in,
                              void* d_out, int out_size, void* d_ws, size_t ws_size,
                              hipStream_t stream)
{
  (void)in_sizes; (void)n_in; (void)out_size;

  const float* x     = (const float*)d_in[0];
  const float* Wp    = (const float*)d_in[1];
  const float* bp    = (const float*)d_in[2];
  const float* phase = (const float*)d_in[3];
  const float* Wq    = (const float*)d_in[4];
  const float* bq    = (const float*)d_in[5];
  const float* Wk    = (const float*)d_in[6];
  const float* bk    = (const float*)d_in[7];
  const float* Wv    = (const float*)d_in[8];
  const float* bv    = (const float*)d_in[9];
  const float* Wo    = (const float*)d_in[10];
  const float* bo    = (const float*)d_in[11];
  const float* temp  = (const float*)d_in[12];
  const float* qscale= (const float*)d_in[13];
  const float* Wf1   = (const float*)d_in[14];
  const float* bf1   = (const float*)d_in[15];
  const float* Wf2   = (const float*)d_in[16];
  const float* bf2   = (const float*)d_in[17];
  const float* n1w   = (const float*)d_in[18];
  const float* n1b   = (const float*)d_in[19];
  const float* n2w   = (const float*)d_in[20];
  const float* n2b   = (const float*)d_in[21];
  const float* skip  = (const float*)d_in[22];
  const float* bn_w  = (const float*)d_in[23];
  const float* bn_b  = (const float*)d_in[24];
  const float* bn_mean=(const float*)d_in[25];
  const float* bn_var= (const float*)d_in[26];
  const float* h1w   = (const float*)d_in[27];
  const float* h1b   = (const float*)d_in[28];
  const float* h2w   = (const float*)d_in[29];
  const float* h2b   = (const float*)d_in[30];
  const float* h3w   = (const float*)d_in[31];
  const float* h3b   = (const float*)d_in[32];
  const float* u1w   = (const float*)d_in[33];
  const float* u1b   = (const float*)d_in[34];
  const float* u2w   = (const float*)d_in[35];
  const float* u2b   = (const float*)d_in[36];

  char* ws = (char*)d_ws;
  size_t off = 0;
  auto alloc = [&](size_t n) -> char* {
    off = (off + 255) & ~(size_t)255;
    char* p = ws + off;
    off += n;
    return p;
  };

  const long M = 131072;

  // ---- fixed allocations ----
  short* h_bf   = (short*)alloc((size_t)M * 288 * 2);
  float* pe_mod = (float*)alloc(128 * 288 * 4);

  short* Wp_b   = (short*)alloc((size_t)384 * 96 * 2);
  short* Wqkv_b = (short*)alloc((size_t)4 * 1152 * 288 * 2);
  short* Wo_b   = (short*)alloc((size_t)4 * 384 * 352 * 2);
  short* Wf1_b  = (short*)alloc((size_t)4 * 1408 * 288 * 2);
  short* Wf2_b  = (short*)alloc((size_t)4 * 384 * 1344 * 2);

  float* bp_p   = (float*)alloc((size_t)384 * 4);
  float* bqkv_p = (float*)alloc((size_t)4 * 1152 * 4);
  float* bo_p   = (float*)alloc((size_t)4 * 384 * 4);
  float* bf1_p  = (float*)alloc((size_t)4 * 1408 * 4);
  float* bf2_p  = (float*)alloc((size_t)4 * 384 * 4);

  // ---- adaptive batch chunking: per-token scratch = 3264 bytes ----
  // R layout (per token): [qkv 2304B | o 704B], aliased: [g 576B | f 2688B], x 192B
  const size_t fixed = off;
  int NC = 1;
  while (NC < 8 && fixed + (size_t)(M / NC) * 3264 + (1u << 20) > ws_size) NC <<= 1;
  const long Mc = M / NC;

  char* R = alloc((size_t)Mc * 3264);
  short* qkv_bf = (short*)R;                              // 3 * 8*Mc*48 shorts
  short* o_bf   = (short*)(R + (size_t)Mc * 2304);        // [Mc][352]
  short* g_bf   = (short*)R;                              // [Mc][288]
  short* f_bf   = (short*)(R + (size_t)Mc * 576);         // [Mc][1344]
  short* x_bfc  = (short*)R;                              // [Mc][96]

  const dim3 blk(256);

  // ---- weight/bias conversion + positional encoding ----
  auto conv_w = [&](const float* s, short* d, int N, int K, int Np, int Kp, int L) {
    const int total = L * Np * Kp;
    conv_w_kernel<<<dim3((total + 255) / 256), blk, 0, stream>>>(s, d, N, K, Np, Kp, total);
  };
  auto conv_b = [&](const float* s, float* d, int N, int Np, int L) {
    const int total = L * Np;
    conv_b_kernel<<<dim3((total + 255) / 256), blk, 0, stream>>>(s, d, N, Np, total);
  };
  conv_w(Wp,  Wp_b,  288,   83, 384,   96, 1);
  conv_wqkv_kernel<<<dim3((4 * 1152 * 288 + 255) / 256), blk, 0, stream>>>(Wq, Wk, Wv, Wqkv_b);
  conv_w(Wo,  Wo_b,  288,  328, 384,  352, 4);
  conv_w(Wf1, Wf1_b, 1315, 288, 1408, 288, 4);
  conv_w(Wf2, Wf2_b, 288, 1315, 384, 1344, 4);
  conv_b(bp,  bp_p,  288,  384, 1);
  conv_bqkv_kernel<<<dim3((4 * 1152 + 255) / 256), blk, 0, stream>>>(bq, bk, bv, bqkv_p);
  conv_b(bo,  bo_p,  288,  384, 4);
  conv_b(bf1, bf1_p, 1315, 1408, 4);
  conv_b(bf2, bf2_p, 288,  384, 4);
  pe_kernel<<<dim3((128 * 288 + 255) / 256), blk, 0, stream>>>(phase, pe_mod);

  auto gemm = [&](int mode, const short* A, const short* Bmat, const float* bias,
                  short* C, const float* pe, short* Cq, int K, int ld, int ldc,
                  int Nstore, int NT, long Mrows) {
    const dim3 grid((unsigned)((Mrows / 128) * NT));
    switch (mode) {
      case 0: gemm_kernel<0><<<grid, blk, 0, stream>>>(A, Bmat, bias, C, pe, Cq, K, ld, ld, ldc, Nstore, NT, (int)Mrows); break;
      case 1: gemm_kernel<1><<<grid, blk, 0, stream>>>(A, Bmat, bias, C, pe, Cq, K, ld, ld, ldc, Nstore, NT, (int)Mrows); break;
      case 2: gemm_kernel<2><<<grid, blk, 0, stream>>>(A, Bmat, bias, C, pe, Cq, K, ld, ld, ldc, Nstore, NT, (int)Mrows); break;
      default: gemm_kernel<3><<<grid, blk, 0, stream>>>(A, Bmat, bias, C, pe, Cq, K, ld, ld, ldc, Nstore, NT, (int)Mrows); break;
    }
  };

  for (int c = 0; c < NC; ++c) {
    const float* x_c = x + (size_t)c * Mc * 83;
    short* h_c = h_bf + (size_t)c * Mc * 288;

    const int xtot = (int)(Mc * 96);
    conv_x_kernel<<<dim3((xtot + 255) / 256), blk, 0, stream>>>(x_c, x_bfc, xtot);

    // input projection + positional encoding
    gemm(2, x_bfc, Wp_b, bp_p, h_c, pe_mod, nullptr, 96, 96, 288, 288, 3, Mc);

    for (int l = 0; l < 4; ++l) {
      const short* Wqkv_l = Wqkv_b + (size_t)l * 1152 * 288;
      const short* Wo_l   = Wo_b   + (size_t)l * 384 * 352;
      const short* Wf1_l  = Wf1_b  + (size_t)l * 1408 * 288;
      const short* Wf2_l  = Wf2_b  + (size_t)l * 384 * 1344;

      // fused QKV -> head-padded [sec][head][Mc][48]
      gemm(3, h_c, Wqkv_l, bqkv_p + l * 1152, nullptr, nullptr, qkv_bf,
           288, 288, 0, 1152, 9, Mc);

      attn_kernel<<<dim3((unsigned)(Mc / 128), 8), blk, 0, stream>>>(
          qkv_bf, o_bf, temp, qscale, l, Mc);

      gemm(0, o_bf, Wo_l, bo_p + l * 384, g_bf, nullptr, nullptr,
           352, 352, 288, 288, 3, Mc);
      ln_kernel<<<dim3((unsigned)(Mc / 4)), blk, 0, stream>>>(
          h_c, g_bf, n1w + l * 288, n1b + l * 288, skip, l, 1);

      gemm(1, h_c, Wf1_l, bf1_p + l * 1408, f_bf, nullptr, nullptr,
           288, 288, 1344, 1344, 11, Mc);
      gemm(0, f_bf, Wf2_l, bf2_p + l * 384, g_bf, nullptr, nullptr,
           1344, 1344, 288, 288, 3, Mc);
      ln_kernel<<<dim3((unsigned)(Mc / 4)), blk, 0, stream>>>(
          h_c, g_bf, n2w + l * 288, n2b + l * 288, skip, l, 0);
    }
  }

  head_kernel<<<dim3(1024), blk, 0, stream>>>(h_bf, (float*)d_out,
      bn_w, bn_b, bn_mean, bn_var,
      h1w, h1b, h2w, h2b, h3w, h3b,
      u1w, u1b, u2w, u2b);
}

// Round 5
// 3948.865 us; speedup vs baseline: 1.3268x; 1.0738x over previous
//
#include <hip/hip_runtime.h>
#include <cstdint>

typedef __attribute__((ext_vector_type(8))) short short8;
typedef __attribute__((ext_vector_type(4))) float floatx4;

#define DEV __device__ __forceinline__

DEV short f2bf(float f) {
  unsigned u = __builtin_bit_cast(unsigned, f);
  u += 0x7fffu + ((u >> 16) & 1u);
  return (short)(u >> 16);
}
DEV float bf2f(short s) {
  unsigned u = ((unsigned)(unsigned short)s) << 16;
  return __builtin_bit_cast(float, u);
}
DEV float gelu_exact(float x) {
  return 0.5f * x * (1.0f + erff(x * 0.70710678118654752f));
}
// tanh-approx gelu via sigmoid identity: 0.5(1+tanh(t)) == sigmoid(2t); |err|<~5e-4
DEV float gelu_fast(float x) {
  const float t2 = 1.5957691216057308f * (x + 0.044715f * x * x * x);
  return x / (1.0f + __expf(-t2));
}
DEV void gload16(const void* g, void* l) {
  __builtin_amdgcn_global_load_lds((const __attribute__((address_space(1))) void*)g,
                                   (__attribute__((address_space(3))) void*)l,
                                   16, 0, 0);
}

// ---------------------------------------------------------------------------
// 128x128-tile bf16 MFMA GEMM.  C[M,N] = A[M,K] * Bw[N,K]^T + bias.
// 1-D grid (MT*NT, XCD-swizzled).  XOR-swizzled LDS staging (0 conflicts,
// verified r4).  Epilogue: C tile staged through LDS (Ct[128][136]) so global
// stores are short8 (256B segments) instead of scalar shorts.
// MODE 0: C = v + bias
// MODE 1: C = gelu_fast(v + bias)
// MODE 2: C = v + bias + pe[(row&127)*288 + col]
// ---------------------------------------------------------------------------
template<int MODE>
__global__ __launch_bounds__(256)
void gemm_kernel(const short* __restrict__ A, const short* __restrict__ Bw,
                 const float* __restrict__ bias, short* __restrict__ C,
                 const float* __restrict__ pe,
                 int K, int lda, int ldb, int ldc, int Nstore, int NT)
{
  __shared__ __align__(16) short lds[128 * 136];
  short* As = lds;                 // [128][32]
  short* Bs = lds + 128 * 32;      // [128][32]
  short* Ct = lds;                 // [128][136] (aliases As/Bs after K-loop)

  const int tid  = threadIdx.x;
  const int wave = tid >> 6, lane = tid & 63;
  const int quad = lane >> 4, r16 = lane & 15;
  const int per = gridDim.x >> 3;                    // grid always %8==0
  const int gti = (blockIdx.x & 7) * per + (blockIdx.x >> 3);
  const int mt = gti / NT, nt = gti - mt * NT;
  const int wm = (wave >> 1) * 64, wn = (wave & 1) * 64;

  const long Abase = (long)mt * 128 * lda;
  const long Bbase = (long)nt * 128 * ldb;

  const int row0 = tid >> 2,         cc0 = (tid & 3) ^ ((row0 >> 1) & 3);
  const int row1 = (256 + tid) >> 2, cc1 = ((256 + tid) & 3) ^ ((row1 >> 1) & 3);

  floatx4 acc[4][4] = {};

  for (int k0 = 0; k0 < K; k0 += 32) {
    __syncthreads();
    gload16(A  + Abase + (long)row0 * lda + k0 + cc0 * 8, &As[(0 * 256 + wave * 64) * 8]);
    gload16(A  + Abase + (long)row1 * lda + k0 + cc1 * 8, &As[(1 * 256 + wave * 64) * 8]);
    gload16(Bw + Bbase + (long)row0 * ldb + k0 + cc0 * 8, &Bs[(0 * 256 + wave * 64) * 8]);
    gload16(Bw + Bbase + (long)row1 * ldb + k0 + cc1 * 8, &Bs[(1 * 256 + wave * 64) * 8]);
    __syncthreads();

    short8 af[4], bfr[4];
#pragma unroll
    for (int i = 0; i < 4; ++i) {
      const int R = wm + i * 16 + r16;
      af[i] = *(const short8*)&As[R * 32 + (quad ^ ((R >> 1) & 3)) * 8];
    }
#pragma unroll
    for (int j = 0; j < 4; ++j) {
      const int R = wn + j * 16 + r16;
      bfr[j] = *(const short8*)&Bs[R * 32 + (quad ^ ((R >> 1) & 3)) * 8];
    }
#pragma unroll
    for (int i = 0; i < 4; ++i)
#pragma unroll
      for (int j = 0; j < 4; ++j)
        acc[i][j] = __builtin_amdgcn_mfma_f32_16x16x32_bf16(af[i], bfr[j], acc[i][j], 0, 0, 0);
  }

  const int mb0 = mt * 128, tb = nt * 128;

  // ---- stage C tile (with epilogue math) into Ct[128][136] ----
  __syncthreads();
#pragma unroll
  for (int j = 0; j < 4; ++j) {
    const int col  = wn + j * 16 + r16;
    const int gcol = tb + col;
    const float bv = bias[gcol];
#pragma unroll
    for (int i = 0; i < 4; ++i) {
#pragma unroll
      for (int rg = 0; rg < 4; ++rg) {
        const int r = wm + i * 16 + quad * 4 + rg;
        float v = acc[i][j][rg] + bv;
        if (MODE == 1) v = gelu_fast(v);
        if (MODE == 2) v += pe[((mb0 + r) & 127) * 288 + gcol];
        Ct[r * 136 + col] = f2bf(v);
      }
    }
  }
  __syncthreads();

  // ---- vectorized write-out: 2048 chunks of 8 shorts ----
#pragma unroll
  for (int rr = 0; rr < 8; ++rr) {
    const int chunk = rr * 256 + tid;
    const int row = chunk >> 4, ch = chunk & 15;
    const int gcol = tb + ch * 8;
    if (gcol < Nstore)
      *(short8*)(C + (long)(mb0 + row) * ldc + gcol) = *(const short8*)&Ct[row * 136 + ch * 8];
  }
}

// ---------------------------------------------------------------------------
// Attention: one block per (b, head).  S=128, D_HEAD=41 (padded to 48 in
// global: qkv [Mc][1152], col (sec*8+head)*48+d, pads are true zeros).
// LDS: qs/ks stride 72 (K-dim = 64-padded d); vsT/Pb stride 136 (K-dim = s).
// ---------------------------------------------------------------------------
__global__ __launch_bounds__(256)
void attn_kernel(const short* __restrict__ qkv, short* __restrict__ og,
                 const float* __restrict__ temp, const float* __restrict__ qscale,
                 int layer, long Mc)
{
  __shared__ __align__(16) short qk[2 * 128 * 72];   // qs|ks, later Pb[128][136]
  __shared__ __align__(16) short vsT[64 * 136];      // [d][s]
  __shared__ float red[2][2][64];

  short* qs = qk;
  short* ks = qk + 128 * 72;
  short* Pb = qk;

  const int b = blockIdx.x, h = blockIdx.y;
  const int tid = threadIdx.x;
  const short* qg = qkv + (long)(b * 128) * 1152 + h * 48;
  const short* kg = qg + 384;
  const short* vg = qg + 768;

  // q,k rows: 8 chunks each (dc 0..5 real — pads already zero in global)
  for (int c = tid; c < 1024; c += 256) {
    const int s = c >> 3, dc = c & 7;
    short8 tq, tk;
    if (dc < 6) {
      tq = *(const short8*)(qg + (long)s * 1152 + dc * 8);
      tk = *(const short8*)(kg + (long)s * 1152 + dc * 8);
    } else {
#pragma unroll
      for (int j = 0; j < 8; ++j) { tq[j] = 0; tk[j] = 0; }
    }
    *(short8*)&qs[s * 72 + dc * 8] = tq;
    *(short8*)&ks[s * 72 + dc * 8] = tk;
  }
  // v transposed into vsT[d][s]
  for (int c = tid; c < 768; c += 256) {
    const int s = c / 6, dc = c - (c / 6) * 6;
    short8 tv = *(const short8*)(vg + (long)s * 1152 + dc * 8);
#pragma unroll
    for (int j = 0; j < 8; ++j) vsT[(dc * 8 + j) * 136 + s] = tv[j];
  }
  __syncthreads();

  const int wave = tid >> 6, lane = tid & 63;
  const int quad = lane >> 4, r16 = lane & 15;
  const int wm = (wave >> 1) * 64, wn = (wave & 1) * 64;
  const int rh = wave >> 1, ch = wave & 1;
  const float invs = 1.0f / (6.4031242374328485f * temp[layer]); // 1/(sqrt(41)*temp)
  const float qsc  = qscale[layer * 8 + h];

  // ---- scores = Q K^T * invs (registers) ----
  floatx4 acc[4][4] = {};
#pragma unroll
  for (int kk = 0; kk < 2; ++kk) {
    const int k0 = kk * 32;
    short8 af[4], bfr[4];
#pragma unroll
    for (int i = 0; i < 4; ++i)
      af[i] = *(const short8*)&qs[(wm + i * 16 + r16) * 72 + k0 + quad * 8];
#pragma unroll
    for (int j = 0; j < 4; ++j)
      bfr[j] = *(const short8*)&ks[(wn + j * 16 + r16) * 72 + k0 + quad * 8];
#pragma unroll
    for (int i = 0; i < 4; ++i)
#pragma unroll
      for (int j = 0; j < 4; ++j)
        acc[i][j] = __builtin_amdgcn_mfma_f32_16x16x32_bf16(af[i], bfr[j], acc[i][j], 0, 0, 0);
  }
#pragma unroll
  for (int i = 0; i < 4; ++i)
#pragma unroll
    for (int j = 0; j < 4; ++j)
#pragma unroll
      for (int rg = 0; rg < 4; ++rg)
        acc[i][j][rg] *= invs;

  // ---- softmax row max ----
  float rmax[4][4];
#pragma unroll
  for (int i = 0; i < 4; ++i)
#pragma unroll
    for (int rg = 0; rg < 4; ++rg) {
      float m = acc[i][0][rg];
#pragma unroll
      for (int j = 1; j < 4; ++j) m = fmaxf(m, acc[i][j][rg]);
      rmax[i][rg] = m;
    }
#pragma unroll
  for (int msk = 1; msk < 16; msk <<= 1)
#pragma unroll
    for (int i = 0; i < 4; ++i)
#pragma unroll
      for (int rg = 0; rg < 4; ++rg)
        rmax[i][rg] = fmaxf(rmax[i][rg], __shfl_xor(rmax[i][rg], msk));
  if (r16 == 0)
#pragma unroll
    for (int i = 0; i < 4; ++i)
#pragma unroll
      for (int rg = 0; rg < 4; ++rg)
        red[rh][ch][i * 16 + quad * 4 + rg] = rmax[i][rg];
  __syncthreads();
#pragma unroll
  for (int i = 0; i < 4; ++i)
#pragma unroll
    for (int rg = 0; rg < 4; ++rg) {
      const int r = i * 16 + quad * 4 + rg;
      rmax[i][rg] = fmaxf(red[rh][0][r], red[rh][1][r]);
    }

  // ---- exp + row sum ----
  float rsum[4][4] = {};
#pragma unroll
  for (int i = 0; i < 4; ++i)
#pragma unroll
    for (int j = 0; j < 4; ++j)
#pragma unroll
      for (int rg = 0; rg < 4; ++rg) {
        const float e = __expf(acc[i][j][rg] - rmax[i][rg]);
        acc[i][j][rg] = e;
        rsum[i][rg] += e;
      }
#pragma unroll
  for (int msk = 1; msk < 16; msk <<= 1)
#pragma unroll
    for (int i = 0; i < 4; ++i)
#pragma unroll
      for (int rg = 0; rg < 4; ++rg)
        rsum[i][rg] += __shfl_xor(rsum[i][rg], msk);
  __syncthreads();
  if (r16 == 0)
#pragma unroll
    for (int i = 0; i < 4; ++i)
#pragma unroll
      for (int rg = 0; rg < 4; ++rg)
        red[rh][ch][i * 16 + quad * 4 + rg] = rsum[i][rg];
  __syncthreads();
#pragma unroll
  for (int i = 0; i < 4; ++i)
#pragma unroll
    for (int rg = 0; rg < 4; ++rg) {
      const int r = i * 16 + quad * 4 + rg;
      rmax[i][rg] = qsc / (red[rh][0][r] + red[rh][1][r]);  // rowscale
    }

  // ---- write P (bf16, stride 136) over qs/ks ----
#pragma unroll
  for (int i = 0; i < 4; ++i)
#pragma unroll
    for (int rg = 0; rg < 4; ++rg) {
      const int r = wm + i * 16 + quad * 4 + rg;
#pragma unroll
      for (int j = 0; j < 4; ++j)
        Pb[r * 136 + wn + j * 16 + r16] = f2bf(acc[i][j][rg] * rmax[i][rg]);
    }
  __syncthreads();

  // ---- O = P V ----
  const int om = (wave >> 1) * 64, on = (wave & 1) * 32;
  floatx4 oacc[4][2] = {};
#pragma unroll
  for (int kk = 0; kk < 4; ++kk) {
    const int k0 = kk * 32;
    short8 af[4], bfr[2];
#pragma unroll
    for (int i = 0; i < 4; ++i)
      af[i] = *(const short8*)&Pb[(om + i * 16 + r16) * 136 + k0 + quad * 8];
#pragma unroll
    for (int j = 0; j < 2; ++j)
      bfr[j] = *(const short8*)&vsT[(on + j * 16 + r16) * 136 + k0 + quad * 8];
#pragma unroll
    for (int i = 0; i < 4; ++i)
#pragma unroll
      for (int j = 0; j < 2; ++j)
        oacc[i][j] = __builtin_amdgcn_mfma_f32_16x16x32_bf16(af[i], bfr[j], oacc[i][j], 0, 0, 0);
  }
  const long obase = ((long)b * 128) * 352 + h * 41;
#pragma unroll
  for (int i = 0; i < 4; ++i)
#pragma unroll
    for (int j = 0; j < 2; ++j)
#pragma unroll
      for (int rg = 0; rg < 4; ++rg) {
        const int sq = om + i * 16 + quad * 4 + rg;
        const int d  = on + j * 16 + r16;
        if (d < 41) og[obase + (long)sq * 352 + d] = f2bf(oacc[i][j][rg]);
      }

  // zero pad cols 328..351 of o (read as A by the Wo GEMM)
  if (h == 0) {
    for (int idx = tid; idx < 128 * 24; idx += 256) {
      const int s = idx / 24, c = idx - (idx / 24) * 24;
      og[((long)b * 128 + s) * 352 + 328 + c] = 0;
    }
  }
}

// ---------------------------------------------------------------------------
// LayerNorm: hb = LN(hb + skip * g) * w + b.  Wave per row (36 active lanes,
// short8 vector loads/stores), 4 rows/block.
// ---------------------------------------------------------------------------
__global__ __launch_bounds__(256)
void ln_kernel(short* __restrict__ hb, const short* __restrict__ g,
               const float* __restrict__ w, const float* __restrict__ bb,
               const float* __restrict__ skip_p, int layer, int use_skip)
{
  const int row  = blockIdx.x * 4 + (threadIdx.x >> 6);
  const int lane = threadIdx.x & 63;
  const float skipv = use_skip ? skip_p[layer] : 1.0f;
  const long base = (long)row * 288 + lane * 8;

  float xv[8];
  float sum = 0.f, sum2 = 0.f;
  if (lane < 36) {
    const short8 hv = *(const short8*)(hb + base);
    const short8 gv = *(const short8*)(g + base);
#pragma unroll
    for (int j = 0; j < 8; ++j) {
      const float v = bf2f(hv[j]) + skipv * bf2f(gv[j]);
      xv[j] = v;
      sum += v; sum2 += v * v;
    }
  } else {
#pragma unroll
    for (int j = 0; j < 8; ++j) xv[j] = 0.f;
  }
#pragma unroll
  for (int m = 1; m < 64; m <<= 1) {
    sum  += __shfl_xor(sum, m);
    sum2 += __shfl_xor(sum2, m);
  }
  const float mean = sum * (1.f / 288.f);
  const float var  = sum2 * (1.f / 288.f) - mean * mean;
  const float rstd = rsqrtf(var + 1e-5f);
  if (lane < 36) {
    short8 o;
#pragma unroll
    for (int j = 0; j < 8; ++j)
      o[j] = f2bf((xv[j] - mean) * rstd * w[lane * 8 + j] + bb[lane * 8 + j]);
    *(short8*)(hb + base) = o;
  }
}

// ---------------------------------------------------------------------------
// Pool over S + BN + GELU MLP head + uncertainty head.  Block per b.
// ---------------------------------------------------------------------------
__global__ __launch_bounds__(256)
void head_kernel(const short* __restrict__ hb, float* __restrict__ out,
                 const float* bn_w, const float* bn_b, const float* bn_mean, const float* bn_var,
                 const float* h1w, const float* h1b, const float* h2w, const float* h2b,
                 const float* h3w, const float* h3b,
                 const float* u1w, const float* u1b, const float* u2w, const float* u2b)
{
  __shared__ float pooled[288], z[288], z1[144], z2[72], uu[72];
  const int b = blockIdx.x, tid = threadIdx.x;

  float a0 = 0.f, a1 = 0.f;
  for (int s = 0; s < 128; ++s) {
    const long ro = ((long)b * 128 + s) * 288;
    a0 += bf2f(hb[ro + tid]);
    if (tid < 32) a1 += bf2f(hb[ro + 256 + tid]);
  }
  pooled[tid] = a0 * (1.f / 128.f);
  if (tid < 32) pooled[256 + tid] = a1 * (1.f / 128.f);
  __syncthreads();

  for (int d = tid; d < 288; d += 256) {
    const float p = pooled[d];
    z[d] = gelu_exact((p - bn_mean[d]) * rsqrtf(bn_var[d] + 1e-5f) * bn_w[d] + bn_b[d]);
  }
  __syncthreads();

  if (tid < 144) {
    float s = h1b[tid];
    for (int k = 0; k < 288; ++k) s += z[k] * h1w[tid * 288 + k];
    z1[tid] = gelu_exact(s);
  } else if (tid < 216) {
    const int t = tid - 144;
    float s = u1b[t];
    for (int k = 0; k < 288; ++k) s += pooled[k] * u1w[t * 288 + k];
    uu[t] = fmaxf(s, 0.f);
  }
  __syncthreads();

  if (tid < 72) {
    float s = h2b[tid];
    for (int k = 0; k < 144; ++k) s += z1[k] * h2w[tid * 144 + k];
    z2[tid] = gelu_exact(s);
  }
  __syncthreads();

  if (tid == 0) {
    float s = h3b[0];
    for (int k = 0; k < 72; ++k) s += z2[k] * h3w[k];
    out[b] = s;
  }
  if (tid == 64) {
    float s = u2b[0];
    for (int k = 0; k < 72; ++k) s += uu[k] * u2w[k];
    out[1024 + b] = (s > 20.f) ? s : log1pf(__expf(s));
  }
}

// ---------------------------------------------------------------------------
// Conversion / padding kernels
// ---------------------------------------------------------------------------
__global__ void conv_w_kernel(const float* __restrict__ src, short* __restrict__ dst,
                              int N, int K, int Npad, int Kpad, int total)
{
  const int i = blockIdx.x * 256 + threadIdx.x;
  if (i >= total) return;
  const int kk = i % Kpad;
  const int t  = i / Kpad;
  const int n  = t % Npad;
  const int l  = t / Npad;
  const float v = (n < N && kk < K) ? src[((long)l * N + n) * K + kk] : 0.f;
  dst[i] = f2bf(v);
}

__global__ void conv_b_kernel(const float* __restrict__ src, float* __restrict__ dst,
                              int N, int Npad, int total)
{
  const int i = blockIdx.x * 256 + threadIdx.x;
  if (i >= total) return;
  const int n = i % Npad, l = i / Npad;
  dst[i] = (n < N) ? src[l * N + n] : 0.f;
}

// fused QKV weight, head-padded rows: r' = (sec*8+head)*48 + d, d<48
// (d<41 real -> original row head*41+d of W_sec; d>=41 zero)
__global__ void conv_wqkv_kernel(const float* __restrict__ Wq, const float* __restrict__ Wk,
                                 const float* __restrict__ Wv, short* __restrict__ dst)
{
  const int i = blockIdx.x * 256 + threadIdx.x;
  if (i >= 4 * 1152 * 288) return;
  const int kk = i % 288;
  const int t  = i / 288;
  const int r  = t % 1152;
  const int l  = t / 1152;
  const int g  = r / 48, d = r - (r / 48) * 48;
  const int sec = g >> 3, head = g & 7;
  float v = 0.f;
  if (d < 41) {
    const float* W = (sec == 0) ? Wq : (sec == 1) ? Wk : Wv;
    v = W[((long)l * 328 + head * 41 + d) * 288 + kk];
  }
  dst[i] = f2bf(v);
}

__global__ void conv_bqkv_kernel(const float* __restrict__ bq, const float* __restrict__ bk,
                                 const float* __restrict__ bv, float* __restrict__ dst)
{
  const int i = blockIdx.x * 256 + threadIdx.x;
  if (i >= 4 * 1152) return;
  const int r = i % 1152, l = i / 1152;
  const int g = r / 48, d = r - (r / 48) * 48;
  const int sec = g >> 3, head = g & 7;
  float v = 0.f;
  if (d < 41) {
    const float* b = (sec == 0) ? bq : (sec == 1) ? bk : bv;
    v = b[l * 328 + head * 41 + d];
  }
  dst[i] = v;
}

__global__ void conv_x_kernel(const float* __restrict__ x, short* __restrict__ xb, int total)
{
  const int i = blockIdx.x * 256 + threadIdx.x;
  if (i >= total) return;
  const int c = i % 96;
  const int r = i / 96;
  xb[i] = f2bf((c < 83) ? x[(long)r * 83 + c] : 0.f);
}

__global__ void pe_kernel(const float* __restrict__ phase, float* __restrict__ pe_mod)
{
  const int i = blockIdx.x * 256 + threadIdx.x;
  if (i >= 128 * 288) return;
  const int d = i % 288, s = i / 288;
  const int pair = d >> 1;
  const float divv = expf((float)(2 * pair) * (-9.210340371976184f / 288.f));
  const float arg = (float)s * divv;
  const float v = (d & 1) ? cosf(arg) : sinf(arg);
  pe_mod[i] = v * cosf(phase[d]);
}

// ---------------------------------------------------------------------------
extern "C" void kernel_launch(void* const* d_in, const int* in_sizes, int n_in,
                              void* d_out, int out_size, void* d_ws, size_t ws_size,
                              hipStream_t stream)
{
  (void)in_sizes; (void)n_in; (void)out_size;

  const float* x     = (const float*)d_in[0];
  const float* Wp    = (const float*)d_in[1];
  const float* bp    = (const float*)d_in[2];
  const float* phase = (const float*)d_in[3];
  const float* Wq    = (const float*)d_in[4];
  const float* bq    = (const float*)d_in[5];
  const float* Wk    = (const float*)d_in[6];
  const float* bk    = (const float*)d_in[7];
  const float* Wv    = (const float*)d_in[8];
  const float* bv    = (const float*)d_in[9];
  const float* Wo    = (const float*)d_in[10];
  const float* bo    = (const float*)d_in[11];
  const float* temp  = (const float*)d_in[12];
  const float* qscale= (const float*)d_in[13];
  const float* Wf1   = (const float*)d_in[14];
  const float* bf1   = (const float*)d_in[15];
  const float* Wf2   = (const float*)d_in[16];
  const float* bf2   = (const float*)d_in[17];
  const float* n1w   = (const float*)d_in[18];
  const float* n1b   = (const float*)d_in[19];
  const float* n2w   = (const float*)d_in[20];
  const float* n2b   = (const float*)d_in[21];
  const float* skip  = (const float*)d_in[22];
  const float* bn_w  = (const float*)d_in[23];
  const float* bn_b  = (const float*)d_in[24];
  const float* bn_mean=(const float*)d_in[25];
  const float* bn_var= (const float*)d_in[26];
  const float* h1w   = (const float*)d_in[27];
  const float* h1b   = (const float*)d_in[28];
  const float* h2w   = (const float*)d_in[29];
  const float* h2b   = (const float*)d_in[30];
  const float* h3w   = (const float*)d_in[31];
  const float* h3b   = (const float*)d_in[32];
  const float* u1w   = (const float*)d_in[33];
  const float* u1b   = (const float*)d_in[34];
  const float* u2w   = (const float*)d_in[35];
  const float* u2b   = (const float*)d_in[36];

  char* ws = (char*)d_ws;
  size_t off = 0;
  auto alloc = [&](size_t n) -> char* {
    off = (off + 255) & ~(size_t)255;
    char* p = ws + off;
    off += n;
    return p;
  };

  const long M = 131072;

  // ---- fixed allocations ----
  short* h_bf   = (short*)alloc((size_t)M * 288 * 2);
  float* pe_mod = (float*)alloc(128 * 288 * 4);

  short* Wp_b   = (short*)alloc((size_t)384 * 96 * 2);
  short* Wqkv_b = (short*)alloc((size_t)4 * 1152 * 288 * 2);
  short* Wo_b   = (short*)alloc((size_t)4 * 384 * 352 * 2);
  short* Wf1_b  = (short*)alloc((size_t)4 * 1408 * 288 * 2);
  short* Wf2_b  = (short*)alloc((size_t)4 * 384 * 1344 * 2);

  float* bp_p   = (float*)alloc((size_t)384 * 4);
  float* bqkv_p = (float*)alloc((size_t)4 * 1152 * 4);
  float* bo_p   = (float*)alloc((size_t)4 * 384 * 4);
  float* bf1_p  = (float*)alloc((size_t)4 * 1408 * 4);
  float* bf2_p  = (float*)alloc((size_t)4 * 384 * 4);

  // ---- adaptive batch chunking: per-token scratch = 3264 bytes ----
  // R layout (per token): [qkv 2304B | o 704B]; aliases: g=R[0,576), f=R[576,3264), x=R[0,192)
  const size_t fixed = off;
  int NC = 1;
  while (NC < 8 && fixed + (size_t)(M / NC) * 3264 + (1u << 20) > ws_size) NC <<= 1;
  const long Mc = M / NC;

  char* R = alloc((size_t)Mc * 3264);
  short* qkv_bf = (short*)R;                              // [Mc][1152]
  short* o_bf   = (short*)(R + (size_t)Mc * 2304);        // [Mc][352]
  short* g_bf   = (short*)R;                              // [Mc][288]
  short* f_bf   = (short*)(R + (size_t)Mc * 576);         // [Mc][1344]
  short* x_bfc  = (short*)R;                              // [Mc][96]

  const dim3 blk(256);

  // ---- weight/bias conversion + positional encoding ----
  auto conv_w = [&](const float* s, short* d, int N, int K, int Np, int Kp, int L) {
    const int total = L * Np * Kp;
    conv_w_kernel<<<dim3((total + 255) / 256), blk, 0, stream>>>(s, d, N, K, Np, Kp, total);
  };
  auto conv_b = [&](const float* s, float* d, int N, int Np, int L) {
    const int total = L * Np;
    conv_b_kernel<<<dim3((total + 255) / 256), blk, 0, stream>>>(s, d, N, Np, total);
  };
  conv_w(Wp,  Wp_b,  288,   83, 384,   96, 1);
  conv_wqkv_kernel<<<dim3((4 * 1152 * 288 + 255) / 256), blk, 0, stream>>>(Wq, Wk, Wv, Wqkv_b);
  conv_w(Wo,  Wo_b,  288,  328, 384,  352, 4);
  conv_w(Wf1, Wf1_b, 1315, 288, 1408, 288, 4);
  conv_w(Wf2, Wf2_b, 288, 1315, 384, 1344, 4);
  conv_b(bp,  bp_p,  288,  384, 1);
  conv_bqkv_kernel<<<dim3((4 * 1152 + 255) / 256), blk, 0, stream>>>(bq, bk, bv, bqkv_p);
  conv_b(bo,  bo_p,  288,  384, 4);
  conv_b(bf1, bf1_p, 1315, 1408, 4);
  conv_b(bf2, bf2_p, 288,  384, 4);
  pe_kernel<<<dim3((128 * 288 + 255) / 256), blk, 0, stream>>>(phase, pe_mod);

  auto gemm = [&](int mode, const short* A, const short* Bmat, const float* bias,
                  short* C, const float* pe, int K, int ld, int ldc,
                  int Nstore, int NT, long Mrows) {
    const dim3 grid((unsigned)((Mrows / 128) * NT));
    switch (mode) {
      case 0: gemm_kernel<0><<<grid, blk, 0, stream>>>(A, Bmat, bias, C, pe, K, ld, ld, ldc, Nstore, NT); break;
      case 1: gemm_kernel<1><<<grid, blk, 0, stream>>>(A, Bmat, bias, C, pe, K, ld, ld, ldc, Nstore, NT); break;
      default: gemm_kernel<2><<<grid, blk, 0, stream>>>(A, Bmat, bias, C, pe, K, ld, ld, ldc, Nstore, NT); break;
    }
  };

  for (int c = 0; c < NC; ++c) {
    const float* x_c = x + (size_t)c * Mc * 83;
    short* h_c = h_bf + (size_t)c * Mc * 288;

    const int xtot = (int)(Mc * 96);
    conv_x_kernel<<<dim3((xtot + 255) / 256), blk, 0, stream>>>(x_c, x_bfc, xtot);

    // input projection + positional encoding
    gemm(2, x_bfc, Wp_b, bp_p, h_c, pe_mod, 96, 96, 288, 288, 3, Mc);

    for (int l = 0; l < 4; ++l) {
      const short* Wqkv_l = Wqkv_b + (size_t)l * 1152 * 288;
      const short* Wo_l   = Wo_b   + (size_t)l * 384 * 352;
      const short* Wf1_l  = Wf1_b  + (size_t)l * 1408 * 288;
      const short* Wf2_l  = Wf2_b  + (size_t)l * 384 * 1344;

      // fused QKV -> head-padded [Mc][1152] (pads are true zeros)
      gemm(0, h_c, Wqkv_l, bqkv_p + l * 1152, qkv_bf, nullptr,
           288, 288, 1152, 1152, 9, Mc);

      attn_kernel<<<dim3((unsigned)(Mc / 128), 8), blk, 0, stream>>>(
          qkv_bf, o_bf, temp, qscale, l, Mc);

      gemm(0, o_bf, Wo_l, bo_p + l * 384, g_bf, nullptr,
           352, 352, 288, 288, 3, Mc);
      ln_kernel<<<dim3((unsigned)(Mc / 4)), blk, 0, stream>>>(
          h_c, g_bf, n1w + l * 288, n1b + l * 288, skip, l, 1);

      gemm(1, h_c, Wf1_l, bf1_p + l * 1408, f_bf, nullptr,
           288, 288, 1344, 1344, 11, Mc);
      gemm(0, f_bf, Wf2_l, bf2_p + l * 384, g_bf, nullptr,
           1344, 1344, 288, 288, 3, Mc);
      ln_kernel<<<dim3((unsigned)(Mc / 4)), blk, 0, stream>>>(
          h_c, g_bf, n2w + l * 288, n2b + l * 288, skip, l, 0);
    }
  }

  head_kernel<<<dim3(1024), blk, 0, stream>>>(h_bf, (float*)d_out,
      bn_w, bn_b, bn_mean, bn_var,
      h1w, h1b, h2w, h2b, h3w, h3b,
      u1w, u1b, u2w, u2b);
}

// Round 6
// 3937.984 us; speedup vs baseline: 1.3304x; 1.0028x over previous
//
#include <hip/hip_runtime.h>
#include <cstdint>

typedef __attribute__((ext_vector_type(8))) short short8;
typedef __attribute__((ext_vector_type(4))) float floatx4;

#define DEV __device__ __forceinline__

DEV short f2bf(float f) {
  unsigned u = __builtin_bit_cast(unsigned, f);
  u += 0x7fffu + ((u >> 16) & 1u);
  return (short)(u >> 16);
}
DEV float bf2f(short s) {
  unsigned u = ((unsigned)(unsigned short)s) << 16;
  return __builtin_bit_cast(float, u);
}
DEV float gelu_exact(float x) {
  return 0.5f * x * (1.0f + erff(x * 0.70710678118654752f));
}
// tanh-approx gelu via sigmoid identity; |err|<~5e-4 (verified r4: absmax unchanged)
DEV float gelu_fast(float x) {
  const float t2 = 1.5957691216057308f * (x + 0.044715f * x * x * x);
  return x / (1.0f + __expf(-t2));
}
DEV void gload16(const void* g, void* l) {
  __builtin_amdgcn_global_load_lds((const __attribute__((address_space(1))) void*)g,
                                   (__attribute__((address_space(3))) void*)l,
                                   16, 0, 0);
}

// ---------------------------------------------------------------------------
// 128x128-tile bf16 MFMA GEMM (QKV / FFN1 / input proj).
// MODE 0: C = v + bias ; MODE 1: C = gelu_fast(v + bias) ;
// MODE 2: C = v + bias + pe[(row&127)*288 + col]
// ---------------------------------------------------------------------------
template<int MODE>
__global__ __launch_bounds__(256)
void gemm_kernel(const short* __restrict__ A, const short* __restrict__ Bw,
                 const float* __restrict__ bias, short* __restrict__ C,
                 const float* __restrict__ pe,
                 int K, int lda, int ldb, int ldc, int Nstore, int NT)
{
  __shared__ __align__(16) short lds[128 * 136];
  short* As = lds;                 // [128][32]
  short* Bs = lds + 128 * 32;      // [128][32]
  short* Ct = lds;                 // [128][136] (aliases after K-loop)

  const int tid  = threadIdx.x;
  const int wave = tid >> 6, lane = tid & 63;
  const int quad = lane >> 4, r16 = lane & 15;
  const int per = gridDim.x >> 3;
  const int gti = (blockIdx.x & 7) * per + (blockIdx.x >> 3);
  const int mt = gti / NT, nt = gti - mt * NT;
  const int wm = (wave >> 1) * 64, wn = (wave & 1) * 64;

  const long Abase = (long)mt * 128 * lda;
  const long Bbase = (long)nt * 128 * ldb;

  const int row0 = tid >> 2,         cc0 = (tid & 3) ^ ((row0 >> 1) & 3);
  const int row1 = (256 + tid) >> 2, cc1 = ((256 + tid) & 3) ^ ((row1 >> 1) & 3);

  floatx4 acc[4][4] = {};

  for (int k0 = 0; k0 < K; k0 += 32) {
    __syncthreads();
    gload16(A  + Abase + (long)row0 * lda + k0 + cc0 * 8, &As[(0 * 256 + wave * 64) * 8]);
    gload16(A  + Abase + (long)row1 * lda + k0 + cc1 * 8, &As[(1 * 256 + wave * 64) * 8]);
    gload16(Bw + Bbase + (long)row0 * ldb + k0 + cc0 * 8, &Bs[(0 * 256 + wave * 64) * 8]);
    gload16(Bw + Bbase + (long)row1 * ldb + k0 + cc1 * 8, &Bs[(1 * 256 + wave * 64) * 8]);
    __syncthreads();

    short8 af[4], bfr[4];
#pragma unroll
    for (int i = 0; i < 4; ++i) {
      const int R = wm + i * 16 + r16;
      af[i] = *(const short8*)&As[R * 32 + (quad ^ ((R >> 1) & 3)) * 8];
    }
#pragma unroll
    for (int j = 0; j < 4; ++j) {
      const int R = wn + j * 16 + r16;
      bfr[j] = *(const short8*)&Bs[R * 32 + (quad ^ ((R >> 1) & 3)) * 8];
    }
#pragma unroll
    for (int i = 0; i < 4; ++i)
#pragma unroll
      for (int j = 0; j < 4; ++j)
        acc[i][j] = __builtin_amdgcn_mfma_f32_16x16x32_bf16(af[i], bfr[j], acc[i][j], 0, 0, 0);
  }

  const int mb0 = mt * 128, tb = nt * 128;

  __syncthreads();
#pragma unroll
  for (int j = 0; j < 4; ++j) {
    const int col  = wn + j * 16 + r16;
    const int gcol = tb + col;
    const float bv = bias[gcol];
#pragma unroll
    for (int i = 0; i < 4; ++i) {
#pragma unroll
      for (int rg = 0; rg < 4; ++rg) {
        const int r = wm + i * 16 + quad * 4 + rg;
        float v = acc[i][j][rg] + bv;
        if (MODE == 1) v = gelu_fast(v);
        if (MODE == 2) v += pe[((mb0 + r) & 127) * 288 + gcol];
        Ct[r * 136 + col] = f2bf(v);
      }
    }
  }
  __syncthreads();

#pragma unroll
  for (int rr = 0; rr < 8; ++rr) {
    const int chunk = rr * 256 + tid;
    const int row = chunk >> 4, ch = chunk & 15;
    const int gcol = tb + ch * 8;
    if (gcol < Nstore)
      *(short8*)(C + (long)(mb0 + row) * ldc + gcol) = *(const short8*)&Ct[row * 136 + ch * 8];
  }
}

// ---------------------------------------------------------------------------
// Fused GEMM + residual + LayerNorm for N=288 exact (Wo+LN1, FFN2+LN2).
// h = LN(h + skipv*(A@Bw^T + bias)) * lnw + lnb, written in place.
// M-tile 64, 4 waves x 16 rows x 18 col-tiles (acc 18 x floatx4).
// Row stats via 16-lane shfl_xor (C-layout: row=quad*4+rg across r16 lanes).
// ---------------------------------------------------------------------------
__global__ __launch_bounds__(256)
void gemm_ln_kernel(const short* __restrict__ A, const short* __restrict__ Bw,
                    const float* __restrict__ bias, short* __restrict__ h,
                    const float* __restrict__ lnw, const float* __restrict__ lnb,
                    const float* __restrict__ skip_p, int layer, int use_skip,
                    int K, int lda, int ldb)
{
  __shared__ __align__(16) short lds[64 * 296];      // max(As+Bs=11264, Hs=18944)
  short* As = lds;                 // [64][32]
  short* Bs = lds + 64 * 32;       // [288][32]
  short* Hs = lds;                 // [64][296] (aliases after K-loop)

  const int tid  = threadIdx.x;
  const int wave = tid >> 6, lane = tid & 63;
  const int quad = lane >> 4, r16 = lane & 15;
  const int mt = blockIdx.x;
  const long Abase = (long)mt * 64 * lda;
  const long mrow0 = (long)mt * 64;

  floatx4 acc[18] = {};

  for (int k0 = 0; k0 < K; k0 += 32) {
    __syncthreads();
    // stage A (chunks 0..255) + B (chunks 256..1407)
    for (int c = tid; c < 1408; c += 256) {
      const void* src;
      if (c < 256) {
        const int row = c >> 2, cc = (c & 3) ^ ((row >> 1) & 3);
        src = A + Abase + (long)row * lda + k0 + cc * 8;
      } else {
        const int cb = c - 256;
        const int row = cb >> 2, cc = (cb & 3) ^ ((row >> 1) & 3);
        src = Bw + (long)row * ldb + k0 + cc * 8;
      }
      gload16(src, &lds[(size_t)(c & ~63) * 8]);
    }
    __syncthreads();

    const int Ra = wave * 16 + r16;
    const short8 af = *(const short8*)&As[Ra * 32 + (quad ^ ((Ra >> 1) & 3)) * 8];
#pragma unroll
    for (int t = 0; t < 18; ++t) {
      const int Rb = t * 16 + r16;
      const short8 bfr = *(const short8*)&Bs[Rb * 32 + (quad ^ ((Rb >> 1) & 3)) * 8];
      acc[t] = __builtin_amdgcn_mfma_f32_16x16x32_bf16(af, bfr, acc[t], 0, 0, 0);
    }
  }

  // ---- stage h_old into Hs (coalesced) ----
  __syncthreads();
  for (int c = tid; c < 2304; c += 256) {
    const int row = c / 36, ch = c - row * 36;
    *(short8*)&Hs[row * 296 + ch * 8] =
        *(const short8*)(h + (mrow0 + row) * 288 + ch * 8);
  }
  __syncthreads();

  const float skipv = use_skip ? skip_p[layer] : 1.0f;
  const int wbase = wave * 16;

  // ---- y = h_old + skipv*(acc + bias); in-register row stats ----
  float ps[4] = {}, pss[4] = {};
#pragma unroll
  for (int t = 0; t < 18; ++t) {
    const int col = t * 16 + r16;
    const float bv = bias[col];
#pragma unroll
    for (int rg = 0; rg < 4; ++rg) {
      const int r = wbase + quad * 4 + rg;
      const float y = bf2f(Hs[r * 296 + col]) + skipv * (acc[t][rg] + bv);
      acc[t][rg] = y;
      ps[rg] += y; pss[rg] += y * y;
    }
  }
#pragma unroll
  for (int m = 1; m < 16; m <<= 1)
#pragma unroll
    for (int rg = 0; rg < 4; ++rg) {
      ps[rg]  += __shfl_xor(ps[rg], m);
      pss[rg] += __shfl_xor(pss[rg], m);
    }
  float mean[4], rstd[4];
#pragma unroll
  for (int rg = 0; rg < 4; ++rg) {
    mean[rg] = ps[rg] * (1.f / 288.f);
    const float var = pss[rg] * (1.f / 288.f) - mean[rg] * mean[rg];
    rstd[rg] = rsqrtf(var + 1e-5f);
  }
#pragma unroll
  for (int t = 0; t < 18; ++t) {
    const int col = t * 16 + r16;
    const float lw = lnw[col], lb = lnb[col];
#pragma unroll
    for (int rg = 0; rg < 4; ++rg) {
      const int r = wbase + quad * 4 + rg;
      Hs[r * 296 + col] = f2bf((acc[t][rg] - mean[rg]) * rstd[rg] * lw + lb);
    }
  }
  __syncthreads();

  // ---- coalesced write-back ----
  for (int c = tid; c < 2304; c += 256) {
    const int row = c / 36, ch = c - row * 36;
    *(short8*)(h + (mrow0 + row) * 288 + ch * 8) =
        *(const short8*)&Hs[row * 296 + ch * 8];
  }
}

// ---------------------------------------------------------------------------
// Attention: one block per (b, head).  qkv [Mc][1152], col (sec*8+head)*48+d.
// ---------------------------------------------------------------------------
__global__ __launch_bounds__(256)
void attn_kernel(const short* __restrict__ qkv, short* __restrict__ og,
                 const float* __restrict__ temp, const float* __restrict__ qscale,
                 int layer, long Mc)
{
  __shared__ __align__(16) short qk[2 * 128 * 72];   // qs|ks, later Pb[128][136]
  __shared__ __align__(16) short vsT[64 * 136];      // [d][s]
  __shared__ float red[2][2][64];

  short* qs = qk;
  short* ks = qk + 128 * 72;
  short* Pb = qk;

  const int b = blockIdx.x, h = blockIdx.y;
  const int tid = threadIdx.x;
  const short* qg = qkv + (long)(b * 128) * 1152 + h * 48;
  const short* kg = qg + 384;
  const short* vg = qg + 768;

  for (int c = tid; c < 1024; c += 256) {
    const int s = c >> 3, dc = c & 7;
    short8 tq, tk;
    if (dc < 6) {
      tq = *(const short8*)(qg + (long)s * 1152 + dc * 8);
      tk = *(const short8*)(kg + (long)s * 1152 + dc * 8);
    } else {
#pragma unroll
      for (int j = 0; j < 8; ++j) { tq[j] = 0; tk[j] = 0; }
    }
    *(short8*)&qs[s * 72 + dc * 8] = tq;
    *(short8*)&ks[s * 72 + dc * 8] = tk;
  }
  for (int c = tid; c < 768; c += 256) {
    const int s = c / 6, dc = c - (c / 6) * 6;
    short8 tv = *(const short8*)(vg + (long)s * 1152 + dc * 8);
#pragma unroll
    for (int j = 0; j < 8; ++j) vsT[(dc * 8 + j) * 136 + s] = tv[j];
  }
  __syncthreads();

  const int wave = tid >> 6, lane = tid & 63;
  const int quad = lane >> 4, r16 = lane & 15;
  const int wm = (wave >> 1) * 64, wn = (wave & 1) * 64;
  const int rh = wave >> 1, ch = wave & 1;
  const float invs = 1.0f / (6.4031242374328485f * temp[layer]);
  const float qsc  = qscale[layer * 8 + h];

  floatx4 acc[4][4] = {};
#pragma unroll
  for (int kk = 0; kk < 2; ++kk) {
    const int k0 = kk * 32;
    short8 af[4], bfr[4];
#pragma unroll
    for (int i = 0; i < 4; ++i)
      af[i] = *(const short8*)&qs[(wm + i * 16 + r16) * 72 + k0 + quad * 8];
#pragma unroll
    for (int j = 0; j < 4; ++j)
      bfr[j] = *(const short8*)&ks[(wn + j * 16 + r16) * 72 + k0 + quad * 8];
#pragma unroll
    for (int i = 0; i < 4; ++i)
#pragma unroll
      for (int j = 0; j < 4; ++j)
        acc[i][j] = __builtin_amdgcn_mfma_f32_16x16x32_bf16(af[i], bfr[j], acc[i][j], 0, 0, 0);
  }
#pragma unroll
  for (int i = 0; i < 4; ++i)
#pragma unroll
    for (int j = 0; j < 4; ++j)
#pragma unroll
      for (int rg = 0; rg < 4; ++rg)
        acc[i][j][rg] *= invs;

  float rmax[4][4];
#pragma unroll
  for (int i = 0; i < 4; ++i)
#pragma unroll
    for (int rg = 0; rg < 4; ++rg) {
      float m = acc[i][0][rg];
#pragma unroll
      for (int j = 1; j < 4; ++j) m = fmaxf(m, acc[i][j][rg]);
      rmax[i][rg] = m;
    }
#pragma unroll
  for (int msk = 1; msk < 16; msk <<= 1)
#pragma unroll
    for (int i = 0; i < 4; ++i)
#pragma unroll
      for (int rg = 0; rg < 4; ++rg)
        rmax[i][rg] = fmaxf(rmax[i][rg], __shfl_xor(rmax[i][rg], msk));
  if (r16 == 0)
#pragma unroll
    for (int i = 0; i < 4; ++i)
#pragma unroll
      for (int rg = 0; rg < 4; ++rg)
        red[rh][ch][i * 16 + quad * 4 + rg] = rmax[i][rg];
  __syncthreads();
#pragma unroll
  for (int i = 0; i < 4; ++i)
#pragma unroll
    for (int rg = 0; rg < 4; ++rg) {
      const int r = i * 16 + quad * 4 + rg;
      rmax[i][rg] = fmaxf(red[rh][0][r], red[rh][1][r]);
    }

  float rsum[4][4] = {};
#pragma unroll
  for (int i = 0; i < 4; ++i)
#pragma unroll
    for (int j = 0; j < 4; ++j)
#pragma unroll
      for (int rg = 0; rg < 4; ++rg) {
        const float e = __expf(acc[i][j][rg] - rmax[i][rg]);
        acc[i][j][rg] = e;
        rsum[i][rg] += e;
      }
#pragma unroll
  for (int msk = 1; msk < 16; msk <<= 1)
#pragma unroll
    for (int i = 0; i < 4; ++i)
#pragma unroll
      for (int rg = 0; rg < 4; ++rg)
        rsum[i][rg] += __shfl_xor(rsum[i][rg], msk);
  __syncthreads();
  if (r16 == 0)
#pragma unroll
    for (int i = 0; i < 4; ++i)
#pragma unroll
      for (int rg = 0; rg < 4; ++rg)
        red[rh][ch][i * 16 + quad * 4 + rg] = rsum[i][rg];
  __syncthreads();
#pragma unroll
  for (int i = 0; i < 4; ++i)
#pragma unroll
    for (int rg = 0; rg < 4; ++rg) {
      const int r = i * 16 + quad * 4 + rg;
      rmax[i][rg] = qsc / (red[rh][0][r] + red[rh][1][r]);
    }

#pragma unroll
  for (int i = 0; i < 4; ++i)
#pragma unroll
    for (int rg = 0; rg < 4; ++rg) {
      const int r = wm + i * 16 + quad * 4 + rg;
#pragma unroll
      for (int j = 0; j < 4; ++j)
        Pb[r * 136 + wn + j * 16 + r16] = f2bf(acc[i][j][rg] * rmax[i][rg]);
    }
  __syncthreads();

  const int om = (wave >> 1) * 64, on = (wave & 1) * 32;
  floatx4 oacc[4][2] = {};
#pragma unroll
  for (int kk = 0; kk < 4; ++kk) {
    const int k0 = kk * 32;
    short8 af[4], bfr[2];
#pragma unroll
    for (int i = 0; i < 4; ++i)
      af[i] = *(const short8*)&Pb[(om + i * 16 + r16) * 136 + k0 + quad * 8];
#pragma unroll
    for (int j = 0; j < 2; ++j)
      bfr[j] = *(const short8*)&vsT[(on + j * 16 + r16) * 136 + k0 + quad * 8];
#pragma unroll
    for (int i = 0; i < 4; ++i)
#pragma unroll
      for (int j = 0; j < 2; ++j)
        oacc[i][j] = __builtin_amdgcn_mfma_f32_16x16x32_bf16(af[i], bfr[j], oacc[i][j], 0, 0, 0);
  }
  const long obase = ((long)b * 128) * 352 + h * 41;
#pragma unroll
  for (int i = 0; i < 4; ++i)
#pragma unroll
    for (int j = 0; j < 2; ++j)
#pragma unroll
      for (int rg = 0; rg < 4; ++rg) {
        const int sq = om + i * 16 + quad * 4 + rg;
        const int d  = on + j * 16 + r16;
        if (d < 41) og[obase + (long)sq * 352 + d] = f2bf(oacc[i][j][rg]);
      }

  if (h == 0) {
    for (int idx = tid; idx < 128 * 24; idx += 256) {
      const int s = idx / 24, c = idx - (idx / 24) * 24;
      og[((long)b * 128 + s) * 352 + 328 + c] = 0;
    }
  }
}

// ---------------------------------------------------------------------------
// Pool over S (parallel, vectorized) + BN + GELU MLP head + uncertainty head.
// Block per b.
// ---------------------------------------------------------------------------
__global__ __launch_bounds__(256)
void head_kernel(const short* __restrict__ hb, float* __restrict__ out,
                 const float* bn_w, const float* bn_b, const float* bn_mean, const float* bn_var,
                 const float* h1w, const float* h1b, const float* h2w, const float* h2b,
                 const float* h3w, const float* h3b,
                 const float* u1w, const float* u1b, const float* u2w, const float* u2b)
{
  __shared__ float psum[252][8];
  __shared__ float pooled[288], z[288], z1[144], z2[72], uu[72];
  const int b = blockIdx.x, tid = threadIdx.x;

  // ---- pooling: 252 threads = 36 col-chunks x 7 row-groups, short8 loads ----
  if (tid < 252) {
    const int cch = tid % 36, grp = tid / 36;
    float a[8];
#pragma unroll
    for (int j = 0; j < 8; ++j) a[j] = 0.f;
    for (int r = grp; r < 128; r += 7) {
      const short8 hv = *(const short8*)(hb + ((long)b * 128 + r) * 288 + cch * 8);
#pragma unroll
      for (int j = 0; j < 8; ++j) a[j] += bf2f(hv[j]);
    }
#pragma unroll
    for (int j = 0; j < 8; ++j) psum[tid][j] = a[j];
  }
  __syncthreads();
  for (int d = tid; d < 288; d += 256) {
    const int cch = d >> 3, j = d & 7;
    float s = 0.f;
#pragma unroll
    for (int g = 0; g < 7; ++g) s += psum[g * 36 + cch][j];
    pooled[d] = s * (1.f / 128.f);
  }
  __syncthreads();

  for (int d = tid; d < 288; d += 256) {
    const float p = pooled[d];
    z[d] = gelu_exact((p - bn_mean[d]) * rsqrtf(bn_var[d] + 1e-5f) * bn_w[d] + bn_b[d]);
  }
  __syncthreads();

  if (tid < 144) {
    float s = h1b[tid];
    for (int k = 0; k < 288; ++k) s += z[k] * h1w[tid * 288 + k];
    z1[tid] = gelu_exact(s);
  } else if (tid < 216) {
    const int t = tid - 144;
    float s = u1b[t];
    for (int k = 0; k < 288; ++k) s += pooled[k] * u1w[t * 288 + k];
    uu[t] = fmaxf(s, 0.f);
  }
  __syncthreads();

  if (tid < 72) {
    float s = h2b[tid];
    for (int k = 0; k < 144; ++k) s += z1[k] * h2w[tid * 144 + k];
    z2[tid] = gelu_exact(s);
  }
  __syncthreads();

  if (tid == 0) {
    float s = h3b[0];
    for (int k = 0; k < 72; ++k) s += z2[k] * h3w[k];
    out[b] = s;
  }
  if (tid == 64) {
    float s = u2b[0];
    for (int k = 0; k < 72; ++k) s += uu[k] * u2w[k];
    out[1024 + b] = (s > 20.f) ? s : log1pf(__expf(s));
  }
}

// ---------------------------------------------------------------------------
// Conversion / padding kernels
// ---------------------------------------------------------------------------
__global__ void conv_w_kernel(const float* __restrict__ src, short* __restrict__ dst,
                              int N, int K, int Npad, int Kpad, int total)
{
  const int i = blockIdx.x * 256 + threadIdx.x;
  if (i >= total) return;
  const int kk = i % Kpad;
  const int t  = i / Kpad;
  const int n  = t % Npad;
  const int l  = t / Npad;
  const float v = (n < N && kk < K) ? src[((long)l * N + n) * K + kk] : 0.f;
  dst[i] = f2bf(v);
}

__global__ void conv_b_kernel(const float* __restrict__ src, float* __restrict__ dst,
                              int N, int Npad, int total)
{
  const int i = blockIdx.x * 256 + threadIdx.x;
  if (i >= total) return;
  const int n = i % Npad, l = i / Npad;
  dst[i] = (n < N) ? src[l * N + n] : 0.f;
}

__global__ void conv_wqkv_kernel(const float* __restrict__ Wq, const float* __restrict__ Wk,
                                 const float* __restrict__ Wv, short* __restrict__ dst)
{
  const int i = blockIdx.x * 256 + threadIdx.x;
  if (i >= 4 * 1152 * 288) return;
  const int kk = i % 288;
  const int t  = i / 288;
  const int r  = t % 1152;
  const int l  = t / 1152;
  const int g  = r / 48, d = r - (r / 48) * 48;
  const int sec = g >> 3, head = g & 7;
  float v = 0.f;
  if (d < 41) {
    const float* W = (sec == 0) ? Wq : (sec == 1) ? Wk : Wv;
    v = W[((long)l * 328 + head * 41 + d) * 288 + kk];
  }
  dst[i] = f2bf(v);
}

__global__ void conv_bqkv_kernel(const float* __restrict__ bq, const float* __restrict__ bk,
                                 const float* __restrict__ bv, float* __restrict__ dst)
{
  const int i = blockIdx.x * 256 + threadIdx.x;
  if (i >= 4 * 1152) return;
  const int r = i % 1152, l = i / 1152;
  const int g = r / 48, d = r - (r / 48) * 48;
  const int sec = g >> 3, head = g & 7;
  float v = 0.f;
  if (d < 41) {
    const float* b = (sec == 0) ? bq : (sec == 1) ? bk : bv;
    v = b[l * 328 + head * 41 + d];
  }
  dst[i] = v;
}

__global__ void conv_x_kernel(const float* __restrict__ x, short* __restrict__ xb, int total)
{
  const int i = blockIdx.x * 256 + threadIdx.x;
  if (i >= total) return;
  const int c = i % 96;
  const int r = i / 96;
  xb[i] = f2bf((c < 83) ? x[(long)r * 83 + c] : 0.f);
}

__global__ void pe_kernel(const float* __restrict__ phase, float* __restrict__ pe_mod)
{
  const int i = blockIdx.x * 256 + threadIdx.x;
  if (i >= 128 * 288) return;
  const int d = i % 288, s = i / 288;
  const int pair = d >> 1;
  const float divv = expf((float)(2 * pair) * (-9.210340371976184f / 288.f));
  const float arg = (float)s * divv;
  const float v = (d & 1) ? cosf(arg) : sinf(arg);
  pe_mod[i] = v * cosf(phase[d]);
}

// ---------------------------------------------------------------------------
extern "C" void kernel_launch(void* const* d_in, const int* in_sizes, int n_in,
                              void* d_out, int out_size, void* d_ws, size_t ws_size,
                              hipStream_t stream)
{
  (void)in_sizes; (void)n_in; (void)out_size;

  const float* x     = (const float*)d_in[0];
  const float* Wp    = (const float*)d_in[1];
  const float* bp    = (const float*)d_in[2];
  const float* phase = (const float*)d_in[3];
  const float* Wq    = (const float*)d_in[4];
  const float* bq    = (const float*)d_in[5];
  const float* Wk    = (const float*)d_in[6];
  const float* bk    = (const float*)d_in[7];
  const float* Wv    = (const float*)d_in[8];
  const float* bv    = (const float*)d_in[9];
  const float* Wo    = (const float*)d_in[10];
  const float* bo    = (const float*)d_in[11];
  const float* temp  = (const float*)d_in[12];
  const float* qscale= (const float*)d_in[13];
  const float* Wf1   = (const float*)d_in[14];
  const float* bf1   = (const float*)d_in[15];
  const float* Wf2   = (const float*)d_in[16];
  const float* bf2   = (const float*)d_in[17];
  const float* n1w   = (const float*)d_in[18];
  const float* n1b   = (const float*)d_in[19];
  const float* n2w   = (const float*)d_in[20];
  const float* n2b   = (const float*)d_in[21];
  const float* skip  = (const float*)d_in[22];
  const float* bn_w  = (const float*)d_in[23];
  const float* bn_b  = (const float*)d_in[24];
  const float* bn_mean=(const float*)d_in[25];
  const float* bn_var= (const float*)d_in[26];
  const float* h1w   = (const float*)d_in[27];
  const float* h1b   = (const float*)d_in[28];
  const float* h2w   = (const float*)d_in[29];
  const float* h2b   = (const float*)d_in[30];
  const float* h3w   = (const float*)d_in[31];
  const float* h3b   = (const float*)d_in[32];
  const float* u1w   = (const float*)d_in[33];
  const float* u1b   = (const float*)d_in[34];
  const float* u2w   = (const float*)d_in[35];
  const float* u2b   = (const float*)d_in[36];

  char* ws = (char*)d_ws;
  size_t off = 0;
  auto alloc = [&](size_t n) -> char* {
    off = (off + 255) & ~(size_t)255;
    char* p = ws + off;
    off += n;
    return p;
  };

  const long M = 131072;

  // ---- fixed allocations ----
  short* h_bf   = (short*)alloc((size_t)M * 288 * 2);
  float* pe_mod = (float*)alloc(128 * 288 * 4);

  short* Wp_b   = (short*)alloc((size_t)384 * 96 * 2);
  short* Wqkv_b = (short*)alloc((size_t)4 * 1152 * 288 * 2);
  short* Wo_b   = (short*)alloc((size_t)4 * 384 * 352 * 2);
  short* Wf1_b  = (short*)alloc((size_t)4 * 1408 * 288 * 2);
  short* Wf2_b  = (short*)alloc((size_t)4 * 384 * 1344 * 2);

  float* bp_p   = (float*)alloc((size_t)384 * 4);
  float* bqkv_p = (float*)alloc((size_t)4 * 1152 * 4);
  float* bo_p   = (float*)alloc((size_t)4 * 384 * 4);
  float* bf1_p  = (float*)alloc((size_t)4 * 1408 * 4);
  float* bf2_p  = (float*)alloc((size_t)4 * 384 * 4);

  // ---- adaptive batch chunking: per-token scratch = 3264 bytes ----
  const size_t fixed = off;
  int NC = 1;
  while (NC < 8 && fixed + (size_t)(M / NC) * 3264 + (1u << 20) > ws_size) NC <<= 1;
  const long Mc = M / NC;

  char* R = alloc((size_t)Mc * 3264);
  short* qkv_bf = (short*)R;                              // [Mc][1152]
  short* o_bf   = (short*)(R + (size_t)Mc * 2304);        // [Mc][352]
  short* f_bf   = (short*)(R + (size_t)Mc * 576);         // [Mc][1344]
  short* x_bfc  = (short*)R;                              // [Mc][96]

  const dim3 blk(256);

  auto conv_w = [&](const float* s, short* d, int N, int K, int Np, int Kp, int L) {
    const int total = L * Np * Kp;
    conv_w_kernel<<<dim3((total + 255) / 256), blk, 0, stream>>>(s, d, N, K, Np, Kp, total);
  };
  auto conv_b = [&](const float* s, float* d, int N, int Np, int L) {
    const int total = L * Np;
    conv_b_kernel<<<dim3((total + 255) / 256), blk, 0, stream>>>(s, d, N, Np, total);
  };
  conv_w(Wp,  Wp_b,  288,   83, 384,   96, 1);
  conv_wqkv_kernel<<<dim3((4 * 1152 * 288 + 255) / 256), blk, 0, stream>>>(Wq, Wk, Wv, Wqkv_b);
  conv_w(Wo,  Wo_b,  288,  328, 384,  352, 4);
  conv_w(Wf1, Wf1_b, 1315, 288, 1408, 288, 4);
  conv_w(Wf2, Wf2_b, 288, 1315, 384, 1344, 4);
  conv_b(bp,  bp_p,  288,  384, 1);
  conv_bqkv_kernel<<<dim3((4 * 1152 + 255) / 256), blk, 0, stream>>>(bq, bk, bv, bqkv_p);
  conv_b(bo,  bo_p,  288,  384, 4);
  conv_b(bf1, bf1_p, 1315, 1408, 4);
  conv_b(bf2, bf2_p, 288,  384, 4);
  pe_kernel<<<dim3((128 * 288 + 255) / 256), blk, 0, stream>>>(phase, pe_mod);

  auto gemm = [&](int mode, const short* A, const short* Bmat, const float* bias,
                  short* C, const float* pe, int K, int ld, int ldc,
                  int Nstore, int NT, long Mrows) {
    const dim3 grid((unsigned)((Mrows / 128) * NT));
    switch (mode) {
      case 0: gemm_kernel<0><<<grid, blk, 0, stream>>>(A, Bmat, bias, C, pe, K, ld, ld, ldc, Nstore, NT); break;
      case 1: gemm_kernel<1><<<grid, blk, 0, stream>>>(A, Bmat, bias, C, pe, K, ld, ld, ldc, Nstore, NT); break;
      default: gemm_kernel<2><<<grid, blk, 0, stream>>>(A, Bmat, bias, C, pe, K, ld, ld, ldc, Nstore, NT); break;
    }
  };

  for (int c = 0; c < NC; ++c) {
    const float* x_c = x + (size_t)c * Mc * 83;
    short* h_c = h_bf + (size_t)c * Mc * 288;

    const int xtot = (int)(Mc * 96);
    conv_x_kernel<<<dim3((xtot + 255) / 256), blk, 0, stream>>>(x_c, x_bfc, xtot);

    // input projection + positional encoding
    gemm(2, x_bfc, Wp_b, bp_p, h_c, pe_mod, 96, 96, 288, 288, 3, Mc);

    for (int l = 0; l < 4; ++l) {
      const short* Wqkv_l = Wqkv_b + (size_t)l * 1152 * 288;
      const short* Wo_l   = Wo_b   + (size_t)l * 384 * 352;
      const short* Wf1_l  = Wf1_b  + (size_t)l * 1408 * 288;
      const short* Wf2_l  = Wf2_b  + (size_t)l * 384 * 1344;

      // fused QKV -> head-padded [Mc][1152]
      gemm(0, h_c, Wqkv_l, bqkv_p + l * 1152, qkv_bf, nullptr,
           288, 288, 1152, 1152, 9, Mc);

      attn_kernel<<<dim3((unsigned)(Mc / 128), 8), blk, 0, stream>>>(
          qkv_bf, o_bf, temp, qscale, l, Mc);

      // Wo + residual + LN1 (fused, writes h in place)
      gemm_ln_kernel<<<dim3((unsigned)(Mc / 64)), blk, 0, stream>>>(
          o_bf, Wo_l, bo_p + l * 384, h_c, n1w + l * 288, n1b + l * 288,
          skip, l, 1, 352, 352, 352);

      gemm(1, h_c, Wf1_l, bf1_p + l * 1408, f_bf, nullptr,
           288, 288, 1344, 1344, 11, Mc);

      // FFN2 + residual + LN2 (fused)
      gemm_ln_kernel<<<dim3((unsigned)(Mc / 64)), blk, 0, stream>>>(
          f_bf, Wf2_l, bf2_p + l * 384, h_c, n2w + l * 288, n2b + l * 288,
          skip, l, 0, 1344, 1344, 1344);
    }
  }

  head_kernel<<<dim3(1024), blk, 0, stream>>>(h_bf, (float*)d_out,
      bn_w, bn_b, bn_mean, bn_var,
      h1w, h1b, h2w, h2b, h3w, h3b,
      u1w, u1b, u2w, u2b);
}